// Round 1
// baseline (902.874 us; speedup 1.0000x reference)
//
#include <hip/hip_runtime.h>
#include <cstdint>

typedef __bf16 bf16;
typedef __bf16 bf16x4 __attribute__((ext_vector_type(4)));
typedef __bf16 bf16x8 __attribute__((ext_vector_type(8)));
typedef float f32x4 __attribute__((ext_vector_type(4)));

#define MROWS 16384
#define DIMH 1024
#define PDIM 512
#define LSEQ 4096

__device__ __forceinline__ float gelu_f(float x) {
  return 0.5f * x * (1.0f + erff(x * 0.70710678118654752f));
}

// ---------------------------------------------------------------- small prep
__global__ void k_prep(const float* __restrict__ Lre, const float* __restrict__ Lim,
                       const float* __restrict__ lstep,
                       float2* __restrict__ lamb, float2* __restrict__ coef) {
  const int p = blockIdx.x * blockDim.x + threadIdx.x;
  if (p >= PDIM) return;
  const float lre = Lre[p], lim = Lim[p];
  const float st = expf(lstep[p]);
  const float er = expf(lre * st);
  const float lbr = er * cosf(lim * st);
  const float lbi = er * sinf(lim * st);
  lamb[p] = make_float2(lbr, lbi);
  const float ar = lbr - 1.0f, ai = lbi;
  const float d = lre * lre + lim * lim;
  coef[p] = make_float2((ar * lre + ai * lim) / d, (ai * lre - ar * lim) / d);
}

__global__ void k_f32_to_bf16(const float* __restrict__ in, bf16* __restrict__ outp, int n) {
  const int i = (blockIdx.x * 256 + threadIdx.x) * 4;
  if (i >= n) return;
  const float4 v = *(const float4*)(in + i);
  bf16x4 o = { (bf16)v.x, (bf16)v.y, (bf16)v.z, (bf16)v.w };
  *(bf16x4*)(outp + i) = o;
}

// bcat: rows 0..511 = Re(B_bar), rows 512..1023 = Im(B_bar); B_bar = coef * (B_re + i B_im)
__global__ void k_bcat(const float* __restrict__ Bre, const float* __restrict__ Bim,
                       const float2* __restrict__ coef, bf16* __restrict__ bcat) {
  const int idx = blockIdx.x * 256 + threadIdx.x;  // 512*1024
  const int p = idx >> 10;
  const float2 c = coef[p];
  const float br = Bre[idx], bi = Bim[idx];
  bcat[idx] = (bf16)(c.x * br - c.y * bi);
  bcat[idx + PDIM * DIMH] = (bf16)(c.x * bi + c.y * br);
}

// ccomb[n][k], k-layout [xsf_re | xsf_im | xsb_re | xsb_im] (each 512)
__global__ void k_ccomb(const float* __restrict__ Cre, const float* __restrict__ Cim,
                        bf16* __restrict__ cc) {
  const int idx = blockIdx.x * 256 + threadIdx.x;  // 1024*2048
  const int n = idx >> 11, k = idx & 2047;
  float v;
  if (k < 512)       v =  2.0f * Cre[n * 1024 + k];
  else if (k < 1024) v = -2.0f * Cim[n * 1024 + (k - 512)];
  else if (k < 1536) v =  2.0f * Cre[n * 1024 + 512 + (k - 1024)];
  else               v = -2.0f * Cim[n * 1024 + 512 + (k - 1536)];
  cc[idx] = (bf16)v;
}

// ---------------------------------------------------------------- GEMM (bt)
// C[M,N] f32 = A[M,K] bf16 @ W[N,K]^T bf16. 128x128 tile, BK=64, 4 waves.
#define BM 128
#define BN 128
#define BK 64
#define LDK 72  // 64 + 8 pad -> 144B row stride, ~2-way LDS conflicts (free)

__global__ __launch_bounds__(256, 2) void k_gemm_bt(const bf16* __restrict__ A,
                                                    const bf16* __restrict__ W,
                                                    float* __restrict__ C,
                                                    int K, int N) {
  const int bn = blockIdx.x, bm = blockIdx.y;
  const int tid = threadIdx.x;
  const int lane = tid & 63;
  const int wave = tid >> 6;
  const int wr = wave >> 1, wc = wave & 1;
  __shared__ bf16 As[BM][LDK];
  __shared__ bf16 Ws[BN][LDK];
  f32x4 acc[4][4];
#pragma unroll
  for (int i = 0; i < 4; ++i)
#pragma unroll
    for (int j = 0; j < 4; ++j) acc[i][j] = (f32x4){0.f, 0.f, 0.f, 0.f};

  const size_t arow = (size_t)bm * BM;
  const size_t wrow = (size_t)bn * BN;
  const int sr = tid >> 3;          // 0..31
  const int scol = (tid & 7) << 3;  // 0..56

  for (int k0 = 0; k0 < K; k0 += BK) {
#pragma unroll
    for (int it = 0; it < 4; ++it) {
      const int r = it * 32 + sr;
      *(uint4*)(&As[r][scol]) = *(const uint4*)(A + (arow + r) * (size_t)K + k0 + scol);
      *(uint4*)(&Ws[r][scol]) = *(const uint4*)(W + (wrow + r) * (size_t)K + k0 + scol);
    }
    __syncthreads();
#pragma unroll
    for (int kk = 0; kk < BK; kk += 32) {
      const int lrow = lane & 15;
      const int lk = kk + ((lane >> 4) << 3);
      bf16x8 af[4], wf[4];
#pragma unroll
      for (int i = 0; i < 4; ++i) af[i] = *(const bf16x8*)(&As[wr * 64 + i * 16 + lrow][lk]);
#pragma unroll
      for (int j = 0; j < 4; ++j) wf[j] = *(const bf16x8*)(&Ws[wc * 64 + j * 16 + lrow][lk]);
#pragma unroll
      for (int i = 0; i < 4; ++i)
#pragma unroll
        for (int j = 0; j < 4; ++j)
          acc[i][j] = __builtin_amdgcn_mfma_f32_16x16x32_bf16(af[i], wf[j], acc[i][j], 0, 0, 0);
    }
    __syncthreads();
  }
  // D layout: col = lane&15, row = (lane>>4)*4 + reg
  const int n0 = (int)wrow + wc * 64 + (lane & 15);
  const size_t m0 = arow + wr * 64 + ((lane >> 4) << 2);
#pragma unroll
  for (int i = 0; i < 4; ++i)
#pragma unroll
    for (int j = 0; j < 4; ++j) {
      const size_t mb = m0 + i * 16;
      const int n = n0 + j * 16;
#pragma unroll
      for (int r = 0; r < 4; ++r) C[(mb + r) * (size_t)N + n] = acc[i][j][r];
    }
}

// ---------------------------------------------------------------- LayerNorm
__global__ __launch_bounds__(256) void k_ln(const float* __restrict__ X,
                                            const float* __restrict__ w,
                                            const float* __restrict__ bb,
                                            float* __restrict__ Yf, bf16* __restrict__ Yb) {
  const int m = blockIdx.x;
  const int tid = threadIdx.x;
  const float4 v = ((const float4*)(X + (size_t)m * DIMH))[tid];
  float s = v.x + v.y + v.z + v.w;
  float s2 = v.x * v.x + v.y * v.y + v.z * v.z + v.w * v.w;
#pragma unroll
  for (int off = 32; off > 0; off >>= 1) { s += __shfl_down(s, off); s2 += __shfl_down(s2, off); }
  __shared__ float rs[4], rq[4];
  if ((tid & 63) == 0) { rs[tid >> 6] = s; rq[tid >> 6] = s2; }
  __syncthreads();
  s = rs[0] + rs[1] + rs[2] + rs[3];
  s2 = rq[0] + rq[1] + rq[2] + rq[3];
  const float mu = s * (1.0f / DIMH);
  const float inv = rsqrtf(s2 * (1.0f / DIMH) - mu * mu + 1e-5f);
  const float4 wv = ((const float4*)w)[tid];
  const float4 bv = ((const float4*)bb)[tid];
  const float o0 = (v.x - mu) * inv * wv.x + bv.x;
  const float o1 = (v.y - mu) * inv * wv.y + bv.y;
  const float o2 = (v.z - mu) * inv * wv.z + bv.z;
  const float o3 = (v.w - mu) * inv * wv.w + bv.w;
  ((float4*)(Yf + (size_t)m * DIMH))[tid] = make_float4(o0, o1, o2, o3);
  bf16x4 ob = { (bf16)o0, (bf16)o1, (bf16)o2, (bf16)o3 };
  *(bf16x4*)(Yb + (size_t)m * DIMH + tid * 4) = ob;
}

// fused: t = gelu(ys + D*fx) + fx ; LN(t) -> Yf (may alias FX), Yb
__global__ __launch_bounds__(256) void k_ln2e(const float* __restrict__ YS,
                                              const float* __restrict__ FX,
                                              const float* __restrict__ Dv,
                                              const float* __restrict__ w,
                                              const float* __restrict__ bb,
                                              float* __restrict__ Yf, bf16* __restrict__ Yb) {
  const int m = blockIdx.x;
  const int tid = threadIdx.x;
  const float4 ys = ((const float4*)(YS + (size_t)m * DIMH))[tid];
  const float4 fx = ((const float4*)(FX + (size_t)m * DIMH))[tid];
  const float4 dv = ((const float4*)Dv)[tid];
  const float t0 = gelu_f(ys.x + dv.x * fx.x) + fx.x;
  const float t1 = gelu_f(ys.y + dv.y * fx.y) + fx.y;
  const float t2 = gelu_f(ys.z + dv.z * fx.z) + fx.z;
  const float t3 = gelu_f(ys.w + dv.w * fx.w) + fx.w;
  float s = t0 + t1 + t2 + t3;
  float s2 = t0 * t0 + t1 * t1 + t2 * t2 + t3 * t3;
#pragma unroll
  for (int off = 32; off > 0; off >>= 1) { s += __shfl_down(s, off); s2 += __shfl_down(s2, off); }
  __shared__ float rs[4], rq[4];
  if ((tid & 63) == 0) { rs[tid >> 6] = s; rq[tid >> 6] = s2; }
  __syncthreads();
  s = rs[0] + rs[1] + rs[2] + rs[3];
  s2 = rq[0] + rq[1] + rq[2] + rq[3];
  const float mu = s * (1.0f / DIMH);
  const float inv = rsqrtf(s2 * (1.0f / DIMH) - mu * mu + 1e-5f);
  const float4 wv = ((const float4*)w)[tid];
  const float4 bv = ((const float4*)bb)[tid];
  const float o0 = (t0 - mu) * inv * wv.x + bv.x;
  const float o1 = (t1 - mu) * inv * wv.y + bv.y;
  const float o2 = (t2 - mu) * inv * wv.z + bv.z;
  const float o3 = (t3 - mu) * inv * wv.w + bv.w;
  ((float4*)(Yf + (size_t)m * DIMH))[tid] = make_float4(o0, o1, o2, o3);
  bf16x4 ob = { (bf16)o0, (bf16)o1, (bf16)o2, (bf16)o3 };
  *(bf16x4*)(Yb + (size_t)m * DIMH + tid * 4) = ob;
}

// ---------------------------------------------------------------- scan
// block = one (b,p); fwd+bwd scans of complex recurrence x[t] = lam*x[t-1] + Bu[t]
#define PH(l) ((l) + ((l) >> 5))

__global__ __launch_bounds__(256) void k_scan(const float* __restrict__ Bu,
                                              const float2* __restrict__ lamb,
                                              bf16* __restrict__ xs) {
  const int b = blockIdx.x >> 9;
  const int p = blockIdx.x & 511;
  __shared__ float bre[4224], bim[4224];
  __shared__ float2 scn[256];
  const int tid = threadIdx.x;
  const size_t base = ((size_t)b * LSEQ) * DIMH + p;
  for (int i = 0; i < 16; ++i) {
    const int l = i * 256 + tid;
    bre[PH(l)] = Bu[base + (size_t)l * DIMH];
    bim[PH(l)] = Bu[base + (size_t)l * DIMH + PDIM];
  }
  __syncthreads();
  const float2 lam = lamb[p];
  float xr[16], xi[16];
  const int l0 = tid * 16;
  // ---------------- forward ----------------
  {
    float sr = 0.f, si = 0.f;
#pragma unroll
    for (int i = 0; i < 16; ++i) {
      const float vr = bre[PH(l0 + i)], vi = bim[PH(l0 + i)];
      const float nr = lam.x * sr - lam.y * si + vr;
      const float ni = lam.x * si + lam.y * sr + vi;
      sr = nr; si = ni; xr[i] = sr; xi[i] = si;
    }
    float mr = lam.x, mi = lam.y;
#pragma unroll
    for (int q = 0; q < 4; ++q) { const float t = mr * mr - mi * mi; mi = 2.f * mr * mi; mr = t; }
    float cr = sr, ci = si;
    scn[tid] = make_float2(cr, ci);
    __syncthreads();
    for (int off = 1; off < 256; off <<= 1) {
      float pr = 0.f, pi = 0.f;
      if (tid >= off) { const float2 o = scn[tid - off]; pr = o.x; pi = o.y; }
      __syncthreads();
      cr += mr * pr - mi * pi;
      ci += mr * pi + mi * pr;
      scn[tid] = make_float2(cr, ci);
      const float t = mr * mr - mi * mi; mi = 2.f * mr * mi; mr = t;
      __syncthreads();
    }
    float er = 0.f, ei = 0.f;
    if (tid > 0) { const float2 o = scn[tid - 1]; er = o.x; ei = o.y; }
    float fr = lam.x, fi = lam.y;
#pragma unroll
    for (int i = 0; i < 16; ++i) {
      xr[i] += fr * er - fi * ei;
      xi[i] += fr * ei + fi * er;
      const float t = fr * lam.x - fi * lam.y;
      fi = fr * lam.y + fi * lam.x; fr = t;
    }
    const size_t orow = ((size_t)b * LSEQ + l0) * 2048;
    for (int i = 0; i < 16; ++i) {
      xs[orow + (size_t)i * 2048 + p] = (bf16)xr[i];
      xs[orow + (size_t)i * 2048 + PDIM + p] = (bf16)xi[i];
    }
  }
  __syncthreads();
  // ---------------- backward ----------------
  {
    float sr = 0.f, si = 0.f;
#pragma unroll
    for (int i = 15; i >= 0; --i) {
      const float vr = bre[PH(l0 + i)], vi = bim[PH(l0 + i)];
      const float nr = lam.x * sr - lam.y * si + vr;
      const float ni = lam.x * si + lam.y * sr + vi;
      sr = nr; si = ni; xr[i] = sr; xi[i] = si;
    }
    float mr = lam.x, mi = lam.y;
#pragma unroll
    for (int q = 0; q < 4; ++q) { const float t = mr * mr - mi * mi; mi = 2.f * mr * mi; mr = t; }
    float cr = sr, ci = si;
    scn[tid] = make_float2(cr, ci);
    __syncthreads();
    for (int off = 1; off < 256; off <<= 1) {
      float pr = 0.f, pi = 0.f;
      if (tid + off < 256) { const float2 o = scn[tid + off]; pr = o.x; pi = o.y; }
      __syncthreads();
      cr += mr * pr - mi * pi;
      ci += mr * pi + mi * pr;
      scn[tid] = make_float2(cr, ci);
      const float t = mr * mr - mi * mi; mi = 2.f * mr * mi; mr = t;
      __syncthreads();
    }
    float er = 0.f, ei = 0.f;
    if (tid < 255) { const float2 o = scn[tid + 1]; er = o.x; ei = o.y; }
    float fr = lam.x, fi = lam.y;
    for (int i = 15; i >= 0; --i) {
      xr[i] += fr * er - fi * ei;
      xi[i] += fr * ei + fi * er;
      const float t = fr * lam.x - fi * lam.y;
      fi = fr * lam.y + fi * lam.x; fr = t;
    }
    const size_t orow = ((size_t)b * LSEQ + l0) * 2048;
    for (int i = 0; i < 16; ++i) {
      xs[orow + (size_t)i * 2048 + 1024 + p] = (bf16)xr[i];
      xs[orow + (size_t)i * 2048 + 1536 + p] = (bf16)xi[i];
    }
  }
}

// ---------------------------------------------------------------- epilogues
__global__ void k_geglu(const float* __restrict__ Ah, const float* __restrict__ Gh,
                        bf16* __restrict__ outb) {
  const size_t i = ((size_t)blockIdx.x * 256 + threadIdx.x) * 4;
  const float4 a = *(const float4*)(Ah + i);
  const float4 g = *(const float4*)(Gh + i);
  bf16x4 o = { (bf16)(a.x * gelu_f(g.x)), (bf16)(a.y * gelu_f(g.y)),
               (bf16)(a.z * gelu_f(g.z)), (bf16)(a.w * gelu_f(g.w)) };
  *(bf16x4*)(outb + i) = o;
}

__global__ void k_addb(const float* __restrict__ Xo, const float* __restrict__ R,
                       bf16* __restrict__ outb) {
  const size_t i = ((size_t)blockIdx.x * 256 + threadIdx.x) * 4;
  const float4 x = *(const float4*)(Xo + i);
  const float4 r = *(const float4*)(R + i);
  bf16x4 o = { (bf16)(x.x + r.x), (bf16)(x.y + r.y), (bf16)(x.z + r.z), (bf16)(x.w + r.w) };
  *(bf16x4*)(outb + i) = o;
}

// ---------------------------------------------------------------- launch
extern "C" void kernel_launch(void* const* d_in, const int* in_sizes, int n_in,
                              void* d_out, int out_size, void* d_ws, size_t ws_size,
                              hipStream_t stream) {
  const float* x    = (const float*)d_in[0];
  const float* W_in = (const float*)d_in[1];
  const float* W_out= (const float*)d_in[2];
  const float* ln1w = (const float*)d_in[3];
  const float* ln1b = (const float*)d_in[4];
  const float* ln2w = (const float*)d_in[5];
  const float* ln2b = (const float*)d_in[6];
  const float* Lre  = (const float*)d_in[7];
  const float* Lim  = (const float*)d_in[8];
  const float* lstep= (const float*)d_in[9];
  const float* Bre  = (const float*)d_in[10];
  const float* Bim  = (const float*)d_in[11];
  const float* Cre  = (const float*)d_in[12];
  const float* Cim  = (const float*)d_in[13];
  const float* Dv   = (const float*)d_in[14];
  const float* ffe  = (const float*)d_in[15];
  const float* ffd  = (const float*)d_in[16];
  float* out = (float*)d_out;
  char* ws = (char*)d_ws;

  bf16* winb   = (bf16*)(ws);
  bf16* woutb  = (bf16*)(ws + (1u << 20));
  bf16* bcat   = (bf16*)(ws + (2u << 20));
  bf16* ccomb  = (bf16*)(ws + (4u << 20));
  bf16* ffeb   = (bf16*)(ws + (8u << 20));
  bf16* ffdb   = (bf16*)(ws + (12u << 20));
  float2* lamb = (float2*)(ws + (14u << 20));
  float2* coef = (float2*)(ws + (14u << 20) + 8192);
  bf16* E      = (bf16*)(ws + (16u << 20));   // 32MB bf16 activation slot
  float* Abuf  = (float*)(ws + (48u << 20));  // 64MB
  float* Bbuf  = (float*)(ws + (112u << 20)); // 64MB
  float* Cbuf  = (float*)(ws + (176u << 20)); // 64MB

  // weight prep (runs every call; deterministic)
  k_prep<<<2, 256, 0, stream>>>(Lre, Lim, lstep, lamb, coef);
  k_f32_to_bf16<<<512, 256, 0, stream>>>(W_in, winb, 524288);
  k_f32_to_bf16<<<512, 256, 0, stream>>>(W_out, woutb, 524288);
  k_f32_to_bf16<<<2048, 256, 0, stream>>>(ffe, ffeb, 2097152);
  k_f32_to_bf16<<<1024, 256, 0, stream>>>(ffd, ffdb, 1048576);
  k_f32_to_bf16<<<8192, 256, 0, stream>>>(x, E, 8388608);  // x_b
  k_bcat<<<2048, 256, 0, stream>>>(Bre, Bim, coef, bcat);
  k_ccomb<<<8192, 256, 0, stream>>>(Cre, Cim, ccomb);

  // h = x @ W_in^T
  k_gemm_bt<<<dim3(8, 128), 256, 0, stream>>>(E, winb, Abuf, 512, 1024);
  // fx = LN1(h) -> Bbuf (f32), E (bf16)
  k_ln<<<16384, 256, 0, stream>>>(Abuf, ln1w, ln1b, Bbuf, E);
  // Bu = fx @ Bcat^T -> Abuf  (cols 0..511 re, 512..1023 im)
  k_gemm_bt<<<dim3(8, 128), 256, 0, stream>>>(E, bcat, Abuf, 1024, 1024);
  // xs (bf16, (M,2048)) -> Cbuf
  k_scan<<<2048, 256, 0, stream>>>(Abuf, lamb, (bf16*)Cbuf);
  // ys = xs @ Ccomb^T -> Abuf
  k_gemm_bt<<<dim3(8, 128), 256, 0, stream>>>((bf16*)Cbuf, ccomb, Abuf, 2048, 1024);
  // x2 = gelu(ys + D*fx) + fx; fx2 = LN2(x2) -> Bbuf (in place), E (bf16)
  k_ln2e<<<16384, 256, 0, stream>>>(Abuf, Bbuf, Dv, ln2w, ln2b, Bbuf, E);
  // ffh halves
  k_gemm_bt<<<dim3(8, 128), 256, 0, stream>>>(E, ffeb, Abuf, 1024, 1024);
  k_gemm_bt<<<dim3(8, 128), 256, 0, stream>>>(E, ffeb + (size_t)1024 * 1024, Cbuf, 1024, 1024);
  // geglu -> E (bf16)
  k_geglu<<<16384, 256, 0, stream>>>(Abuf, Cbuf, E);
  // ffo = geglu @ ffdec^T -> Cbuf
  k_gemm_bt<<<dim3(8, 128), 256, 0, stream>>>(E, ffdb, Cbuf, 1024, 1024);
  // x3_b = bf16(ffo + fx2) -> E
  k_addb<<<16384, 256, 0, stream>>>(Cbuf, Bbuf, E);
  // out = x3 @ W_out^T
  k_gemm_bt<<<dim3(4, 128), 256, 0, stream>>>(E, woutb, out, 1024, 512);
}

// Round 2
// 593.413 us; speedup vs baseline: 1.5215x; 1.5215x over previous
//
#include <hip/hip_runtime.h>
#include <cstdint>

typedef __bf16 bf16;
typedef __bf16 bf16x2 __attribute__((ext_vector_type(2)));
typedef __bf16 bf16x4 __attribute__((ext_vector_type(4)));
typedef __bf16 bf16x8 __attribute__((ext_vector_type(8)));
typedef float f32x4 __attribute__((ext_vector_type(4)));

#define MROWS 16384
#define DIMH 1024
#define PDIM 512
#define LSEQ 4096
#define CL 16
#define NC (LSEQ / CL)  // 256

__device__ __forceinline__ float gelu_f(float x) {
  return 0.5f * x * (1.0f + erff(x * 0.70710678118654752f));
}

// ---------------------------------------------------------------- small prep
__global__ void k_prep(const float* __restrict__ Lre, const float* __restrict__ Lim,
                       const float* __restrict__ lstep,
                       float2* __restrict__ lamb, float2* __restrict__ coef) {
  const int p = blockIdx.x * blockDim.x + threadIdx.x;
  if (p >= PDIM) return;
  const float lre = Lre[p], lim = Lim[p];
  const float st = expf(lstep[p]);
  const float er = expf(lre * st);
  const float lbr = er * cosf(lim * st);
  const float lbi = er * sinf(lim * st);
  lamb[p] = make_float2(lbr, lbi);
  const float ar = lbr - 1.0f, ai = lbi;
  const float d = lre * lre + lim * lim;
  coef[p] = make_float2((ar * lre + ai * lim) / d, (ai * lre - ar * lim) / d);
}

__global__ void k_f32_to_bf16(const float* __restrict__ in, bf16* __restrict__ outp, int n) {
  const int i = (blockIdx.x * 256 + threadIdx.x) * 4;
  if (i >= n) return;
  const float4 v = *(const float4*)(in + i);
  bf16x4 o = { (bf16)v.x, (bf16)v.y, (bf16)v.z, (bf16)v.w };
  *(bf16x4*)(outp + i) = o;
}

// bcat: rows 0..511 = Re(B_bar), rows 512..1023 = Im(B_bar); B_bar = coef * (B_re + i B_im)
__global__ void k_bcat(const float* __restrict__ Bre, const float* __restrict__ Bim,
                       const float2* __restrict__ coef, bf16* __restrict__ bcat) {
  const int idx = blockIdx.x * 256 + threadIdx.x;  // 512*1024
  const int p = idx >> 10;
  const float2 c = coef[p];
  const float br = Bre[idx], bi = Bim[idx];
  bcat[idx] = (bf16)(c.x * br - c.y * bi);
  bcat[idx + PDIM * DIMH] = (bf16)(c.x * bi + c.y * br);
}

// ccomb[n][k], k-layout [xsf_re | xsf_im | xsb_re | xsb_im] (each 512)
__global__ void k_ccomb(const float* __restrict__ Cre, const float* __restrict__ Cim,
                        bf16* __restrict__ cc) {
  const int idx = blockIdx.x * 256 + threadIdx.x;  // 1024*2048
  const int n = idx >> 11, k = idx & 2047;
  float v;
  if (k < 512)       v =  2.0f * Cre[n * 1024 + k];
  else if (k < 1024) v = -2.0f * Cim[n * 1024 + (k - 512)];
  else if (k < 1536) v =  2.0f * Cre[n * 1024 + 512 + (k - 1024)];
  else               v = -2.0f * Cim[n * 1024 + 512 + (k - 1536)];
  cc[idx] = (bf16)v;
}

// ---------------------------------------------------------------- GEMM (bt)
// C[M,N] f32 = A[M,K] bf16 @ W[N,K]^T bf16. 128x128 tile, BK=64, 4 waves.
#define BM 128
#define BN 128
#define BK 64
#define LDKP 72  // 64 + 8 pad -> 144B row stride, ~2-way LDS conflicts (free)

__global__ __launch_bounds__(256, 2) void k_gemm_bt(const bf16* __restrict__ A,
                                                    const bf16* __restrict__ W,
                                                    float* __restrict__ C,
                                                    int K, int N) {
  const int bn = blockIdx.x, bm = blockIdx.y;
  const int tid = threadIdx.x;
  const int lane = tid & 63;
  const int wave = tid >> 6;
  const int wr = wave >> 1, wc = wave & 1;
  __shared__ bf16 As[BM][LDKP];
  __shared__ bf16 Ws[BN][LDKP];
  f32x4 acc[4][4];
#pragma unroll
  for (int i = 0; i < 4; ++i)
#pragma unroll
    for (int j = 0; j < 4; ++j) acc[i][j] = (f32x4){0.f, 0.f, 0.f, 0.f};

  const size_t arow = (size_t)bm * BM;
  const size_t wrow = (size_t)bn * BN;
  const int sr = tid >> 3;          // 0..31
  const int scol = (tid & 7) << 3;  // 0..56

  for (int k0 = 0; k0 < K; k0 += BK) {
#pragma unroll
    for (int it = 0; it < 4; ++it) {
      const int r = it * 32 + sr;
      *(uint4*)(&As[r][scol]) = *(const uint4*)(A + (arow + r) * (size_t)K + k0 + scol);
      *(uint4*)(&Ws[r][scol]) = *(const uint4*)(W + (wrow + r) * (size_t)K + k0 + scol);
    }
    __syncthreads();
#pragma unroll
    for (int kk = 0; kk < BK; kk += 32) {
      const int lrow = lane & 15;
      const int lk = kk + ((lane >> 4) << 3);
      bf16x8 af[4], wf[4];
#pragma unroll
      for (int i = 0; i < 4; ++i) af[i] = *(const bf16x8*)(&As[wr * 64 + i * 16 + lrow][lk]);
#pragma unroll
      for (int j = 0; j < 4; ++j) wf[j] = *(const bf16x8*)(&Ws[wc * 64 + j * 16 + lrow][lk]);
#pragma unroll
      for (int i = 0; i < 4; ++i)
#pragma unroll
        for (int j = 0; j < 4; ++j)
          acc[i][j] = __builtin_amdgcn_mfma_f32_16x16x32_bf16(af[i], wf[j], acc[i][j], 0, 0, 0);
    }
    __syncthreads();
  }
  // D layout: col = lane&15, row = (lane>>4)*4 + reg
  const int n0 = (int)wrow + wc * 64 + (lane & 15);
  const size_t m0 = arow + wr * 64 + ((lane >> 4) << 2);
#pragma unroll
  for (int i = 0; i < 4; ++i)
#pragma unroll
    for (int j = 0; j < 4; ++j) {
      const size_t mb = m0 + i * 16;
      const int n = n0 + j * 16;
#pragma unroll
      for (int r = 0; r < 4; ++r) C[(mb + r) * (size_t)N + n] = acc[i][j][r];
    }
}

// ---------------------------------------------------------------- LayerNorm
__global__ __launch_bounds__(256) void k_ln(const float* __restrict__ X,
                                            const float* __restrict__ w,
                                            const float* __restrict__ bb,
                                            float* __restrict__ Yf, bf16* __restrict__ Yb) {
  const int m = blockIdx.x;
  const int tid = threadIdx.x;
  const float4 v = ((const float4*)(X + (size_t)m * DIMH))[tid];
  float s = v.x + v.y + v.z + v.w;
  float s2 = v.x * v.x + v.y * v.y + v.z * v.z + v.w * v.w;
#pragma unroll
  for (int off = 32; off > 0; off >>= 1) { s += __shfl_down(s, off); s2 += __shfl_down(s2, off); }
  __shared__ float rs[4], rq[4];
  if ((tid & 63) == 0) { rs[tid >> 6] = s; rq[tid >> 6] = s2; }
  __syncthreads();
  s = rs[0] + rs[1] + rs[2] + rs[3];
  s2 = rq[0] + rq[1] + rq[2] + rq[3];
  const float mu = s * (1.0f / DIMH);
  const float inv = rsqrtf(s2 * (1.0f / DIMH) - mu * mu + 1e-5f);
  const float4 wv = ((const float4*)w)[tid];
  const float4 bv = ((const float4*)bb)[tid];
  const float o0 = (v.x - mu) * inv * wv.x + bv.x;
  const float o1 = (v.y - mu) * inv * wv.y + bv.y;
  const float o2 = (v.z - mu) * inv * wv.z + bv.z;
  const float o3 = (v.w - mu) * inv * wv.w + bv.w;
  ((float4*)(Yf + (size_t)m * DIMH))[tid] = make_float4(o0, o1, o2, o3);
  bf16x4 ob = { (bf16)o0, (bf16)o1, (bf16)o2, (bf16)o3 };
  *(bf16x4*)(Yb + (size_t)m * DIMH + tid * 4) = ob;
}

// fused: t = gelu(ys + D*fx) + fx ; LN(t) -> Yf (may alias FX), Yb
__global__ __launch_bounds__(256) void k_ln2e(const float* __restrict__ YS,
                                              const float* __restrict__ FX,
                                              const float* __restrict__ Dv,
                                              const float* __restrict__ w,
                                              const float* __restrict__ bb,
                                              float* __restrict__ Yf, bf16* __restrict__ Yb) {
  const int m = blockIdx.x;
  const int tid = threadIdx.x;
  const float4 ys = ((const float4*)(YS + (size_t)m * DIMH))[tid];
  const float4 fx = ((const float4*)(FX + (size_t)m * DIMH))[tid];
  const float4 dv = ((const float4*)Dv)[tid];
  const float t0 = gelu_f(ys.x + dv.x * fx.x) + fx.x;
  const float t1 = gelu_f(ys.y + dv.y * fx.y) + fx.y;
  const float t2 = gelu_f(ys.z + dv.z * fx.z) + fx.z;
  const float t3 = gelu_f(ys.w + dv.w * fx.w) + fx.w;
  float s = t0 + t1 + t2 + t3;
  float s2 = t0 * t0 + t1 * t1 + t2 * t2 + t3 * t3;
#pragma unroll
  for (int off = 32; off > 0; off >>= 1) { s += __shfl_down(s, off); s2 += __shfl_down(s2, off); }
  __shared__ float rs[4], rq[4];
  if ((tid & 63) == 0) { rs[tid >> 6] = s; rq[tid >> 6] = s2; }
  __syncthreads();
  s = rs[0] + rs[1] + rs[2] + rs[3];
  s2 = rq[0] + rq[1] + rq[2] + rq[3];
  const float mu = s * (1.0f / DIMH);
  const float inv = rsqrtf(s2 * (1.0f / DIMH) - mu * mu + 1e-5f);
  const float4 wv = ((const float4*)w)[tid];
  const float4 bv = ((const float4*)bb)[tid];
  const float o0 = (t0 - mu) * inv * wv.x + bv.x;
  const float o1 = (t1 - mu) * inv * wv.y + bv.y;
  const float o2 = (t2 - mu) * inv * wv.z + bv.z;
  const float o3 = (t3 - mu) * inv * wv.w + bv.w;
  ((float4*)(Yf + (size_t)m * DIMH))[tid] = make_float4(o0, o1, o2, o3);
  bf16x4 ob = { (bf16)o0, (bf16)o1, (bf16)o2, (bf16)o3 };
  *(bf16x4*)(Yb + (size_t)m * DIMH + tid * 4) = ob;
}

// ---------------------------------------------------------------- scan (3-pass)
// Bu layout: (M, 1024) f32, cols [0..512)=re, [512..1024)=im. M = b*4096 + l.
// Thread t owns channels p=2t, 2t+1 (float2 slices of each row -> coalesced).

// Pass A: per (b, chunk) compute fwd+bwd chunk carries.
// carry layout: float2 complex at [(b*NC + c)*2*PDIM + dir*PDIM + p]
__global__ __launch_bounds__(256) void k_scanA(const float* __restrict__ Bu,
                                               const float2* __restrict__ lamb,
                                               float2* __restrict__ carry) {
  const int bc = blockIdx.x;
  const int b = bc >> 8, c = bc & (NC - 1);
  const int t = threadIdx.x;
  const size_t rbase = ((size_t)b * LSEQ + (size_t)c * CL) * DIMH;
  float2 re[CL], im[CL];
#pragma unroll
  for (int i = 0; i < CL; ++i) {
    re[i] = *(const float2*)(Bu + rbase + (size_t)i * DIMH + 2 * t);
    im[i] = *(const float2*)(Bu + rbase + (size_t)i * DIMH + PDIM + 2 * t);
  }
  const float2 l0 = lamb[2 * t];
  const float2 l1 = lamb[2 * t + 1];
  const size_t cb = ((size_t)bc * 2) * PDIM;
  {
    float s0r = 0.f, s0i = 0.f, s1r = 0.f, s1i = 0.f;
#pragma unroll
    for (int i = 0; i < CL; ++i) {
      float nr = l0.x * s0r - l0.y * s0i + re[i].x;
      float ni = l0.x * s0i + l0.y * s0r + im[i].x;
      s0r = nr; s0i = ni;
      nr = l1.x * s1r - l1.y * s1i + re[i].y;
      ni = l1.x * s1i + l1.y * s1r + im[i].y;
      s1r = nr; s1i = ni;
    }
    carry[cb + 2 * t]     = make_float2(s0r, s0i);
    carry[cb + 2 * t + 1] = make_float2(s1r, s1i);
  }
  {
    float s0r = 0.f, s0i = 0.f, s1r = 0.f, s1i = 0.f;
#pragma unroll
    for (int i = CL - 1; i >= 0; --i) {
      float nr = l0.x * s0r - l0.y * s0i + re[i].x;
      float ni = l0.x * s0i + l0.y * s0r + im[i].x;
      s0r = nr; s0i = ni;
      nr = l1.x * s1r - l1.y * s1i + re[i].y;
      ni = l1.x * s1i + l1.y * s1r + im[i].y;
      s1r = nr; s1i = ni;
    }
    carry[cb + PDIM + 2 * t]     = make_float2(s0r, s0i);
    carry[cb + PDIM + 2 * t + 1] = make_float2(s1r, s1i);
  }
}

// Pass B: scan carries across chunks per (b,p); multiplier Lam = lam^CL.
// seed[(b*NC+c)*2*PDIM + dir*PDIM + p] = state entering chunk c for that dir.
__global__ __launch_bounds__(256) void k_scanB(const float2* __restrict__ carry,
                                               const float2* __restrict__ lamb,
                                               float2* __restrict__ seed) {
  const int b = blockIdx.x;  // 4 blocks
  const int t = threadIdx.x;
  const float2 l0 = lamb[2 * t], l1 = lamb[2 * t + 1];
  float L0r = l0.x, L0i = l0.y, L1r = l1.x, L1i = l1.y;
#pragma unroll
  for (int q = 0; q < 4; ++q) {
    float tr = L0r * L0r - L0i * L0i; L0i = 2.f * L0r * L0i; L0r = tr;
    tr = L1r * L1r - L1i * L1i; L1i = 2.f * L1r * L1i; L1r = tr;
  }
  float S0r = 0.f, S0i = 0.f, S1r = 0.f, S1i = 0.f;
  for (int c = 0; c < NC; ++c) {
    const size_t base = (((size_t)b * NC + c) * 2) * PDIM;
    const float2 c0 = carry[base + 2 * t];
    const float2 c1 = carry[base + 2 * t + 1];
    seed[base + 2 * t]     = make_float2(S0r, S0i);
    seed[base + 2 * t + 1] = make_float2(S1r, S1i);
    float nr = L0r * S0r - L0i * S0i + c0.x;
    float ni = L0r * S0i + L0i * S0r + c0.y;
    S0r = nr; S0i = ni;
    nr = L1r * S1r - L1i * S1i + c1.x;
    ni = L1r * S1i + L1i * S1r + c1.y;
    S1r = nr; S1i = ni;
  }
  S0r = 0.f; S0i = 0.f; S1r = 0.f; S1i = 0.f;
  for (int c = NC - 1; c >= 0; --c) {
    const size_t base = (((size_t)b * NC + c) * 2) * PDIM + PDIM;
    const float2 c0 = carry[base + 2 * t];
    const float2 c1 = carry[base + 2 * t + 1];
    seed[base + 2 * t]     = make_float2(S0r, S0i);
    seed[base + 2 * t + 1] = make_float2(S1r, S1i);
    float nr = L0r * S0r - L0i * S0i + c0.x;
    float ni = L0r * S0i + L0i * S0r + c0.y;
    S0r = nr; S0i = ni;
    nr = L1r * S1r - L1i * S1i + c1.x;
    ni = L1r * S1i + L1i * S1r + c1.y;
    S1r = nr; S1i = ni;
  }
}

// Pass C: seeded scans, write xs (M, 2048) bf16 coalesced.
__global__ __launch_bounds__(256) void k_scanC(const float* __restrict__ Bu,
                                               const float2* __restrict__ lamb,
                                               const float2* __restrict__ seed,
                                               bf16* __restrict__ xs) {
  const int bc = blockIdx.x;
  const int b = bc >> 8, c = bc & (NC - 1);
  const int t = threadIdx.x;
  const size_t rbase = ((size_t)b * LSEQ + (size_t)c * CL) * DIMH;
  float2 re[CL], im[CL];
#pragma unroll
  for (int i = 0; i < CL; ++i) {
    re[i] = *(const float2*)(Bu + rbase + (size_t)i * DIMH + 2 * t);
    im[i] = *(const float2*)(Bu + rbase + (size_t)i * DIMH + PDIM + 2 * t);
  }
  const float2 l0 = lamb[2 * t];
  const float2 l1 = lamb[2 * t + 1];
  const size_t sb = ((size_t)bc * 2) * PDIM;
  const size_t obase = ((size_t)b * LSEQ + (size_t)c * CL) * 2048;
  {
    const float2 s0 = seed[sb + 2 * t];
    const float2 s1 = seed[sb + 2 * t + 1];
    float s0r = s0.x, s0i = s0.y, s1r = s1.x, s1i = s1.y;
#pragma unroll
    for (int i = 0; i < CL; ++i) {
      float nr = l0.x * s0r - l0.y * s0i + re[i].x;
      float ni = l0.x * s0i + l0.y * s0r + im[i].x;
      s0r = nr; s0i = ni;
      nr = l1.x * s1r - l1.y * s1i + re[i].y;
      ni = l1.x * s1i + l1.y * s1r + im[i].y;
      s1r = nr; s1i = ni;
      bf16x2 wr2 = { (bf16)s0r, (bf16)s1r };
      bf16x2 wi2 = { (bf16)s0i, (bf16)s1i };
      *(bf16x2*)(xs + obase + (size_t)i * 2048 + 2 * t) = wr2;
      *(bf16x2*)(xs + obase + (size_t)i * 2048 + PDIM + 2 * t) = wi2;
    }
  }
  {
    const float2 s0 = seed[sb + PDIM + 2 * t];
    const float2 s1 = seed[sb + PDIM + 2 * t + 1];
    float s0r = s0.x, s0i = s0.y, s1r = s1.x, s1i = s1.y;
#pragma unroll
    for (int i = CL - 1; i >= 0; --i) {
      float nr = l0.x * s0r - l0.y * s0i + re[i].x;
      float ni = l0.x * s0i + l0.y * s0r + im[i].x;
      s0r = nr; s0i = ni;
      nr = l1.x * s1r - l1.y * s1i + re[i].y;
      ni = l1.x * s1i + l1.y * s1r + im[i].y;
      s1r = nr; s1i = ni;
      bf16x2 wr2 = { (bf16)s0r, (bf16)s1r };
      bf16x2 wi2 = { (bf16)s0i, (bf16)s1i };
      *(bf16x2*)(xs + obase + (size_t)i * 2048 + 1024 + 2 * t) = wr2;
      *(bf16x2*)(xs + obase + (size_t)i * 2048 + 1536 + 2 * t) = wi2;
    }
  }
}

// ---------------------------------------------------------------- epilogues
__global__ void k_geglu(const float* __restrict__ Ah, const float* __restrict__ Gh,
                        bf16* __restrict__ outb) {
  const size_t i = ((size_t)blockIdx.x * 256 + threadIdx.x) * 4;
  const float4 a = *(const float4*)(Ah + i);
  const float4 g = *(const float4*)(Gh + i);
  bf16x4 o = { (bf16)(a.x * gelu_f(g.x)), (bf16)(a.y * gelu_f(g.y)),
               (bf16)(a.z * gelu_f(g.z)), (bf16)(a.w * gelu_f(g.w)) };
  *(bf16x4*)(outb + i) = o;
}

__global__ void k_addb(const float* __restrict__ Xo, const float* __restrict__ R,
                       bf16* __restrict__ outb) {
  const size_t i = ((size_t)blockIdx.x * 256 + threadIdx.x) * 4;
  const float4 x = *(const float4*)(Xo + i);
  const float4 r = *(const float4*)(R + i);
  bf16x4 o = { (bf16)(x.x + r.x), (bf16)(x.y + r.y), (bf16)(x.z + r.z), (bf16)(x.w + r.w) };
  *(bf16x4*)(outb + i) = o;
}

// ---------------------------------------------------------------- launch
extern "C" void kernel_launch(void* const* d_in, const int* in_sizes, int n_in,
                              void* d_out, int out_size, void* d_ws, size_t ws_size,
                              hipStream_t stream) {
  const float* x    = (const float*)d_in[0];
  const float* W_in = (const float*)d_in[1];
  const float* W_out= (const float*)d_in[2];
  const float* ln1w = (const float*)d_in[3];
  const float* ln1b = (const float*)d_in[4];
  const float* ln2w = (const float*)d_in[5];
  const float* ln2b = (const float*)d_in[6];
  const float* Lre  = (const float*)d_in[7];
  const float* Lim  = (const float*)d_in[8];
  const float* lstep= (const float*)d_in[9];
  const float* Bre  = (const float*)d_in[10];
  const float* Bim  = (const float*)d_in[11];
  const float* Cre  = (const float*)d_in[12];
  const float* Cim  = (const float*)d_in[13];
  const float* Dv   = (const float*)d_in[14];
  const float* ffe  = (const float*)d_in[15];
  const float* ffd  = (const float*)d_in[16];
  float* out = (float*)d_out;
  char* ws = (char*)d_ws;

  bf16* winb   = (bf16*)(ws);
  bf16* woutb  = (bf16*)(ws + (1u << 20));
  bf16* bcat   = (bf16*)(ws + (2u << 20));
  bf16* ccomb  = (bf16*)(ws + (4u << 20));
  bf16* ffeb   = (bf16*)(ws + (8u << 20));
  bf16* ffdb   = (bf16*)(ws + (12u << 20));
  float2* lamb = (float2*)(ws + (14u << 20));
  float2* coef = (float2*)(ws + (14u << 20) + 8192);
  bf16* E      = (bf16*)(ws + (16u << 20));   // 32MB bf16 activation slot
  // carry/seed live in E's slot: E is dead between the Bu GEMM and k_ln2e.
  float2* carry = (float2*)(ws + (16u << 20));           // 8 MB
  float2* seed  = (float2*)(ws + (24u << 20));           // 8 MB
  float* Abuf  = (float*)(ws + (48u << 20));  // 64MB
  float* Bbuf  = (float*)(ws + (112u << 20)); // 64MB
  float* Cbuf  = (float*)(ws + (176u << 20)); // 64MB

  // weight prep (runs every call; deterministic)
  k_prep<<<2, 256, 0, stream>>>(Lre, Lim, lstep, lamb, coef);
  k_f32_to_bf16<<<512, 256, 0, stream>>>(W_in, winb, 524288);
  k_f32_to_bf16<<<512, 256, 0, stream>>>(W_out, woutb, 524288);
  k_f32_to_bf16<<<2048, 256, 0, stream>>>(ffe, ffeb, 2097152);
  k_f32_to_bf16<<<1024, 256, 0, stream>>>(ffd, ffdb, 1048576);
  k_f32_to_bf16<<<8192, 256, 0, stream>>>(x, E, 8388608);  // x_b
  k_bcat<<<2048, 256, 0, stream>>>(Bre, Bim, coef, bcat);
  k_ccomb<<<8192, 256, 0, stream>>>(Cre, Cim, ccomb);

  // h = x @ W_in^T
  k_gemm_bt<<<dim3(8, 128), 256, 0, stream>>>(E, winb, Abuf, 512, 1024);
  // fx = LN1(h) -> Bbuf (f32), E (bf16)
  k_ln<<<16384, 256, 0, stream>>>(Abuf, ln1w, ln1b, Bbuf, E);
  // Bu = fx @ Bcat^T -> Abuf  (cols 0..511 re, 512..1023 im)
  k_gemm_bt<<<dim3(8, 128), 256, 0, stream>>>(E, bcat, Abuf, 1024, 1024);
  // xs (bf16, (M,2048)) -> Cbuf via 3-pass chunked scan
  k_scanA<<<4 * NC, 256, 0, stream>>>(Abuf, lamb, carry);
  k_scanB<<<4, 256, 0, stream>>>(carry, lamb, seed);
  k_scanC<<<4 * NC, 256, 0, stream>>>(Abuf, lamb, seed, (bf16*)Cbuf);
  // ys = xs @ Ccomb^T -> Abuf
  k_gemm_bt<<<dim3(8, 128), 256, 0, stream>>>((bf16*)Cbuf, ccomb, Abuf, 2048, 1024);
  // x2 = gelu(ys + D*fx) + fx; fx2 = LN2(x2) -> Bbuf (in place), E (bf16)
  k_ln2e<<<16384, 256, 0, stream>>>(Abuf, Bbuf, Dv, ln2w, ln2b, Bbuf, E);
  // ffh halves
  k_gemm_bt<<<dim3(8, 128), 256, 0, stream>>>(E, ffeb, Abuf, 1024, 1024);
  k_gemm_bt<<<dim3(8, 128), 256, 0, stream>>>(E, ffeb + (size_t)1024 * 1024, Cbuf, 1024, 1024);
  // geglu -> E (bf16)
  k_geglu<<<16384, 256, 0, stream>>>(Abuf, Cbuf, E);
  // ffo = geglu @ ffdec^T -> Cbuf
  k_gemm_bt<<<dim3(8, 128), 256, 0, stream>>>(E, ffdb, Cbuf, 1024, 1024);
  // x3_b = bf16(ffo + fx2) -> E
  k_addb<<<16384, 256, 0, stream>>>(Cbuf, Bbuf, E);
  // out = x3 @ W_out^T
  k_gemm_bt<<<dim3(4, 128), 256, 0, stream>>>(E, woutb, out, 1024, 512);
}

// Round 3
// 588.780 us; speedup vs baseline: 1.5335x; 1.0079x over previous
//
#include <hip/hip_runtime.h>
#include <cstdint>

typedef __bf16 bf16;
typedef __bf16 bf16x2 __attribute__((ext_vector_type(2)));
typedef __bf16 bf16x4 __attribute__((ext_vector_type(4)));
typedef __bf16 bf16x8 __attribute__((ext_vector_type(8)));
typedef float f32x4 __attribute__((ext_vector_type(4)));

#define MROWS 16384
#define DIMH 1024
#define PDIM 512
#define LSEQ 4096
#define CL 16
#define NC (LSEQ / CL)  // 256

typedef const __attribute__((address_space(1))) unsigned int* gas_t;
typedef __attribute__((address_space(3))) unsigned int* las_t;

__device__ __forceinline__ float gelu_f(float x) {
  return 0.5f * x * (1.0f + erff(x * 0.70710678118654752f));
}

// ---------------------------------------------------------------- small prep
__global__ void k_prep(const float* __restrict__ Lre, const float* __restrict__ Lim,
                       const float* __restrict__ lstep,
                       float2* __restrict__ lamb, float2* __restrict__ coef) {
  const int p = blockIdx.x * blockDim.x + threadIdx.x;
  if (p >= PDIM) return;
  const float lre = Lre[p], lim = Lim[p];
  const float st = expf(lstep[p]);
  const float er = expf(lre * st);
  const float lbr = er * cosf(lim * st);
  const float lbi = er * sinf(lim * st);
  lamb[p] = make_float2(lbr, lbi);
  const float ar = lbr - 1.0f, ai = lbi;
  const float d = lre * lre + lim * lim;
  coef[p] = make_float2((ar * lre + ai * lim) / d, (ai * lre - ar * lim) / d);
}

__global__ void k_f32_to_bf16(const float* __restrict__ in, bf16* __restrict__ outp, int n) {
  const int i = (blockIdx.x * 256 + threadIdx.x) * 4;
  if (i >= n) return;
  const float4 v = *(const float4*)(in + i);
  bf16x4 o = { (bf16)v.x, (bf16)v.y, (bf16)v.z, (bf16)v.w };
  *(bf16x4*)(outp + i) = o;
}

// bcat: rows 0..511 = Re(B_bar), rows 512..1023 = Im(B_bar)
__global__ void k_bcat(const float* __restrict__ Bre, const float* __restrict__ Bim,
                       const float2* __restrict__ coef, bf16* __restrict__ bcat) {
  const int idx = blockIdx.x * 256 + threadIdx.x;  // 512*1024
  const int p = idx >> 10;
  const float2 c = coef[p];
  const float br = Bre[idx], bi = Bim[idx];
  bcat[idx] = (bf16)(c.x * br - c.y * bi);
  bcat[idx + PDIM * DIMH] = (bf16)(c.x * bi + c.y * br);
}

// ccomb[n][k], k-layout [xsf_re | xsf_im | xsb_re | xsb_im]
__global__ void k_ccomb(const float* __restrict__ Cre, const float* __restrict__ Cim,
                        bf16* __restrict__ cc) {
  const int idx = blockIdx.x * 256 + threadIdx.x;  // 1024*2048
  const int n = idx >> 11, k = idx & 2047;
  float v;
  if (k < 512)       v =  2.0f * Cre[n * 1024 + k];
  else if (k < 1024) v = -2.0f * Cim[n * 1024 + (k - 512)];
  else if (k < 1536) v =  2.0f * Cre[n * 1024 + 512 + (k - 1024)];
  else               v = -2.0f * Cim[n * 1024 + 512 + (k - 1536)];
  cc[idx] = (bf16)v;
}

// ---------------------------------------------------------------- GEMM
// C[M,N] = A[M,K] bf16 @ W[N,K]^T bf16.  128x128 tile, BK=64, 4 waves,
// global_load_lds width-16 staging (m97 structure) + XCD-locality swizzle.
// EPI: 0 = f32 store; 1 = bf16( auxb * gelu(acc) ); 2 = bf16( acc + auxf );
//      3 = bf16 store.
#define BM 128
#define BN 128
#define BK 64

template <int EPI>
__global__ __launch_bounds__(256) void k_gemm(const bf16* __restrict__ A,
                                              const bf16* __restrict__ W,
                                              float* __restrict__ Cf,
                                              bf16* __restrict__ Cb,
                                              const float* __restrict__ auxf,
                                              const bf16* __restrict__ auxb,
                                              int K, int N, int nbnl) {
  // bijective XCD swizzle (nwg divisible by 8): each XCD gets contiguous rows
  const int q = gridDim.x >> 3;
  const int s = (blockIdx.x & 7) * q + (blockIdx.x >> 3);
  const int bm = s >> nbnl;
  const int bn = s & ((1 << nbnl) - 1);
  const int tid = threadIdx.x;
  const int lane = tid & 63;
  const int wave = tid >> 6;
  const int wr = wave >> 1, wc = wave & 1;
  __shared__ bf16 As[BM][BK];
  __shared__ bf16 Ws[BN][BK];
  f32x4 acc[4][4];
#pragma unroll
  for (int i = 0; i < 4; ++i)
#pragma unroll
    for (int j = 0; j < 4; ++j) acc[i][j] = (f32x4){0.f, 0.f, 0.f, 0.f};

  const size_t arow = (size_t)bm * BM;
  const size_t wrow = (size_t)bn * BN;
  const int srow = lane >> 3;          // 0..7
  const int scol8 = (lane & 7) << 3;   // element offset of 16B chunk

  for (int k0 = 0; k0 < K; k0 += BK) {
#pragma unroll
    for (int it = 0; it < 4; ++it) {
      const int rbase = (it * 4 + wave) * 8;
      __builtin_amdgcn_global_load_lds(
          (gas_t)(A + (arow + rbase + srow) * (size_t)K + k0 + scol8),
          (las_t)(&As[rbase][0]), 16, 0, 0);
      __builtin_amdgcn_global_load_lds(
          (gas_t)(W + (wrow + rbase + srow) * (size_t)K + k0 + scol8),
          (las_t)(&Ws[rbase][0]), 16, 0, 0);
    }
    __syncthreads();
#pragma unroll
    for (int kk = 0; kk < BK; kk += 32) {
      const int lrow = lane & 15;
      const int lk = kk + ((lane >> 4) << 3);
      bf16x8 af[4], wf[4];
#pragma unroll
      for (int i = 0; i < 4; ++i) af[i] = *(const bf16x8*)(&As[wr * 64 + i * 16 + lrow][lk]);
#pragma unroll
      for (int j = 0; j < 4; ++j) wf[j] = *(const bf16x8*)(&Ws[wc * 64 + j * 16 + lrow][lk]);
#pragma unroll
      for (int i = 0; i < 4; ++i)
#pragma unroll
        for (int j = 0; j < 4; ++j)
          acc[i][j] = __builtin_amdgcn_mfma_f32_16x16x32_bf16(af[i], wf[j], acc[i][j], 0, 0, 0);
    }
    __syncthreads();
  }
  // D layout: col = lane&15, row = (lane>>4)*4 + reg
  const int n0 = (int)wrow + wc * 64 + (lane & 15);
  const size_t m0 = arow + wr * 64 + ((lane >> 4) << 2);
#pragma unroll
  for (int i = 0; i < 4; ++i)
#pragma unroll
    for (int j = 0; j < 4; ++j) {
      const size_t mb = m0 + i * 16;
      const int n = n0 + j * 16;
#pragma unroll
      for (int r = 0; r < 4; ++r) {
        const size_t idx = (mb + r) * (size_t)N + n;
        const float v = acc[i][j][r];
        if constexpr (EPI == 0) {
          Cf[idx] = v;
        } else if constexpr (EPI == 1) {
          Cb[idx] = (bf16)((float)auxb[idx] * gelu_f(v));
        } else if constexpr (EPI == 2) {
          Cb[idx] = (bf16)(v + auxf[idx]);
        } else {
          Cb[idx] = (bf16)v;
        }
      }
    }
}

// ---------------------------------------------------------------- LayerNorm
__global__ __launch_bounds__(256) void k_ln(const float* __restrict__ X,
                                            const float* __restrict__ w,
                                            const float* __restrict__ bb,
                                            float* __restrict__ Yf, bf16* __restrict__ Yb) {
  const int m = blockIdx.x;
  const int tid = threadIdx.x;
  const float4 v = ((const float4*)(X + (size_t)m * DIMH))[tid];
  float s = v.x + v.y + v.z + v.w;
  float s2 = v.x * v.x + v.y * v.y + v.z * v.z + v.w * v.w;
#pragma unroll
  for (int off = 32; off > 0; off >>= 1) { s += __shfl_down(s, off); s2 += __shfl_down(s2, off); }
  __shared__ float rs[4], rq[4];
  if ((tid & 63) == 0) { rs[tid >> 6] = s; rq[tid >> 6] = s2; }
  __syncthreads();
  s = rs[0] + rs[1] + rs[2] + rs[3];
  s2 = rq[0] + rq[1] + rq[2] + rq[3];
  const float mu = s * (1.0f / DIMH);
  const float inv = rsqrtf(s2 * (1.0f / DIMH) - mu * mu + 1e-5f);
  const float4 wv = ((const float4*)w)[tid];
  const float4 bv = ((const float4*)bb)[tid];
  const float o0 = (v.x - mu) * inv * wv.x + bv.x;
  const float o1 = (v.y - mu) * inv * wv.y + bv.y;
  const float o2 = (v.z - mu) * inv * wv.z + bv.z;
  const float o3 = (v.w - mu) * inv * wv.w + bv.w;
  ((float4*)(Yf + (size_t)m * DIMH))[tid] = make_float4(o0, o1, o2, o3);
  bf16x4 ob = { (bf16)o0, (bf16)o1, (bf16)o2, (bf16)o3 };
  *(bf16x4*)(Yb + (size_t)m * DIMH + tid * 4) = ob;
}

// fused: t = gelu(ys + D*fx) + fx ; LN(t) -> Yf (aliases FX), Yb
__global__ __launch_bounds__(256) void k_ln2e(const float* __restrict__ YS,
                                              const float* __restrict__ FX,
                                              const float* __restrict__ Dv,
                                              const float* __restrict__ w,
                                              const float* __restrict__ bb,
                                              float* __restrict__ Yf, bf16* __restrict__ Yb) {
  const int m = blockIdx.x;
  const int tid = threadIdx.x;
  const float4 ys = ((const float4*)(YS + (size_t)m * DIMH))[tid];
  const float4 fx = ((const float4*)(FX + (size_t)m * DIMH))[tid];
  const float4 dv = ((const float4*)Dv)[tid];
  const float t0 = gelu_f(ys.x + dv.x * fx.x) + fx.x;
  const float t1 = gelu_f(ys.y + dv.y * fx.y) + fx.y;
  const float t2 = gelu_f(ys.z + dv.z * fx.z) + fx.z;
  const float t3 = gelu_f(ys.w + dv.w * fx.w) + fx.w;
  float s = t0 + t1 + t2 + t3;
  float s2 = t0 * t0 + t1 * t1 + t2 * t2 + t3 * t3;
#pragma unroll
  for (int off = 32; off > 0; off >>= 1) { s += __shfl_down(s, off); s2 += __shfl_down(s2, off); }
  __shared__ float rs[4], rq[4];
  if ((tid & 63) == 0) { rs[tid >> 6] = s; rq[tid >> 6] = s2; }
  __syncthreads();
  s = rs[0] + rs[1] + rs[2] + rs[3];
  s2 = rq[0] + rq[1] + rq[2] + rq[3];
  const float mu = s * (1.0f / DIMH);
  const float inv = rsqrtf(s2 * (1.0f / DIMH) - mu * mu + 1e-5f);
  const float4 wv = ((const float4*)w)[tid];
  const float4 bv = ((const float4*)bb)[tid];
  const float o0 = (t0 - mu) * inv * wv.x + bv.x;
  const float o1 = (t1 - mu) * inv * wv.y + bv.y;
  const float o2 = (t2 - mu) * inv * wv.z + bv.z;
  const float o3 = (t3 - mu) * inv * wv.w + bv.w;
  ((float4*)(Yf + (size_t)m * DIMH))[tid] = make_float4(o0, o1, o2, o3);
  bf16x4 ob = { (bf16)o0, (bf16)o1, (bf16)o2, (bf16)o3 };
  *(bf16x4*)(Yb + (size_t)m * DIMH + tid * 4) = ob;
}

// ---------------------------------------------------------------- scan (3-pass)
__global__ __launch_bounds__(256) void k_scanA(const float* __restrict__ Bu,
                                               const float2* __restrict__ lamb,
                                               float2* __restrict__ carry) {
  const int bc = blockIdx.x;
  const int b = bc >> 8, c = bc & (NC - 1);
  const int t = threadIdx.x;
  const size_t rbase = ((size_t)b * LSEQ + (size_t)c * CL) * DIMH;
  float2 re[CL], im[CL];
#pragma unroll
  for (int i = 0; i < CL; ++i) {
    re[i] = *(const float2*)(Bu + rbase + (size_t)i * DIMH + 2 * t);
    im[i] = *(const float2*)(Bu + rbase + (size_t)i * DIMH + PDIM + 2 * t);
  }
  const float2 l0 = lamb[2 * t];
  const float2 l1 = lamb[2 * t + 1];
  const size_t cb = ((size_t)bc * 2) * PDIM;
  {
    float s0r = 0.f, s0i = 0.f, s1r = 0.f, s1i = 0.f;
#pragma unroll
    for (int i = 0; i < CL; ++i) {
      float nr = l0.x * s0r - l0.y * s0i + re[i].x;
      float ni = l0.x * s0i + l0.y * s0r + im[i].x;
      s0r = nr; s0i = ni;
      nr = l1.x * s1r - l1.y * s1i + re[i].y;
      ni = l1.x * s1i + l1.y * s1r + im[i].y;
      s1r = nr; s1i = ni;
    }
    carry[cb + 2 * t]     = make_float2(s0r, s0i);
    carry[cb + 2 * t + 1] = make_float2(s1r, s1i);
  }
  {
    float s0r = 0.f, s0i = 0.f, s1r = 0.f, s1i = 0.f;
#pragma unroll
    for (int i = CL - 1; i >= 0; --i) {
      float nr = l0.x * s0r - l0.y * s0i + re[i].x;
      float ni = l0.x * s0i + l0.y * s0r + im[i].x;
      s0r = nr; s0i = ni;
      nr = l1.x * s1r - l1.y * s1i + re[i].y;
      ni = l1.x * s1i + l1.y * s1r + im[i].y;
      s1r = nr; s1i = ni;
    }
    carry[cb + PDIM + 2 * t]     = make_float2(s0r, s0i);
    carry[cb + PDIM + 2 * t + 1] = make_float2(s1r, s1i);
  }
}

__global__ __launch_bounds__(256) void k_scanB(const float2* __restrict__ carry,
                                               const float2* __restrict__ lamb,
                                               float2* __restrict__ seed) {
  const int b = blockIdx.x;  // 4 blocks
  const int t = threadIdx.x;
  const float2 l0 = lamb[2 * t], l1 = lamb[2 * t + 1];
  float L0r = l0.x, L0i = l0.y, L1r = l1.x, L1i = l1.y;
#pragma unroll
  for (int q = 0; q < 4; ++q) {
    float tr = L0r * L0r - L0i * L0i; L0i = 2.f * L0r * L0i; L0r = tr;
    tr = L1r * L1r - L1i * L1i; L1i = 2.f * L1r * L1i; L1r = tr;
  }
  float S0r = 0.f, S0i = 0.f, S1r = 0.f, S1i = 0.f;
  for (int c = 0; c < NC; ++c) {
    const size_t base = (((size_t)b * NC + c) * 2) * PDIM;
    const float2 c0 = carry[base + 2 * t];
    const float2 c1 = carry[base + 2 * t + 1];
    seed[base + 2 * t]     = make_float2(S0r, S0i);
    seed[base + 2 * t + 1] = make_float2(S1r, S1i);
    float nr = L0r * S0r - L0i * S0i + c0.x;
    float ni = L0r * S0i + L0i * S0r + c0.y;
    S0r = nr; S0i = ni;
    nr = L1r * S1r - L1i * S1i + c1.x;
    ni = L1r * S1i + L1i * S1r + c1.y;
    S1r = nr; S1i = ni;
  }
  S0r = 0.f; S0i = 0.f; S1r = 0.f; S1i = 0.f;
  for (int c = NC - 1; c >= 0; --c) {
    const size_t base = (((size_t)b * NC + c) * 2) * PDIM + PDIM;
    const float2 c0 = carry[base + 2 * t];
    const float2 c1 = carry[base + 2 * t + 1];
    seed[base + 2 * t]     = make_float2(S0r, S0i);
    seed[base + 2 * t + 1] = make_float2(S1r, S1i);
    float nr = L0r * S0r - L0i * S0i + c0.x;
    float ni = L0r * S0i + L0i * S0r + c0.y;
    S0r = nr; S0i = ni;
    nr = L1r * S1r - L1i * S1i + c1.x;
    ni = L1r * S1i + L1i * S1r + c1.y;
    S1r = nr; S1i = ni;
  }
}

__global__ __launch_bounds__(256) void k_scanC(const float* __restrict__ Bu,
                                               const float2* __restrict__ lamb,
                                               const float2* __restrict__ seed,
                                               bf16* __restrict__ xs) {
  const int bc = blockIdx.x;
  const int b = bc >> 8, c = bc & (NC - 1);
  const int t = threadIdx.x;
  const size_t rbase = ((size_t)b * LSEQ + (size_t)c * CL) * DIMH;
  float2 re[CL], im[CL];
#pragma unroll
  for (int i = 0; i < CL; ++i) {
    re[i] = *(const float2*)(Bu + rbase + (size_t)i * DIMH + 2 * t);
    im[i] = *(const float2*)(Bu + rbase + (size_t)i * DIMH + PDIM + 2 * t);
  }
  const float2 l0 = lamb[2 * t];
  const float2 l1 = lamb[2 * t + 1];
  const size_t sb = ((size_t)bc * 2) * PDIM;
  const size_t obase = ((size_t)b * LSEQ + (size_t)c * CL) * 2048;
  {
    const float2 s0 = seed[sb + 2 * t];
    const float2 s1 = seed[sb + 2 * t + 1];
    float s0r = s0.x, s0i = s0.y, s1r = s1.x, s1i = s1.y;
#pragma unroll
    for (int i = 0; i < CL; ++i) {
      float nr = l0.x * s0r - l0.y * s0i + re[i].x;
      float ni = l0.x * s0i + l0.y * s0r + im[i].x;
      s0r = nr; s0i = ni;
      nr = l1.x * s1r - l1.y * s1i + re[i].y;
      ni = l1.x * s1i + l1.y * s1r + im[i].y;
      s1r = nr; s1i = ni;
      bf16x2 wr2 = { (bf16)s0r, (bf16)s1r };
      bf16x2 wi2 = { (bf16)s0i, (bf16)s1i };
      *(bf16x2*)(xs + obase + (size_t)i * 2048 + 2 * t) = wr2;
      *(bf16x2*)(xs + obase + (size_t)i * 2048 + PDIM + 2 * t) = wi2;
    }
  }
  {
    const float2 s0 = seed[sb + PDIM + 2 * t];
    const float2 s1 = seed[sb + PDIM + 2 * t + 1];
    float s0r = s0.x, s0i = s0.y, s1r = s1.x, s1i = s1.y;
#pragma unroll
    for (int i = CL - 1; i >= 0; --i) {
      float nr = l0.x * s0r - l0.y * s0i + re[i].x;
      float ni = l0.x * s0i + l0.y * s0r + im[i].x;
      s0r = nr; s0i = ni;
      nr = l1.x * s1r - l1.y * s1i + re[i].y;
      ni = l1.x * s1i + l1.y * s1r + im[i].y;
      s1r = nr; s1i = ni;
      bf16x2 wr2 = { (bf16)s0r, (bf16)s1r };
      bf16x2 wi2 = { (bf16)s0i, (bf16)s1i };
      *(bf16x2*)(xs + obase + (size_t)i * 2048 + 1024 + 2 * t) = wr2;
      *(bf16x2*)(xs + obase + (size_t)i * 2048 + 1536 + 2 * t) = wi2;
    }
  }
}

// ---------------------------------------------------------------- launch
extern "C" void kernel_launch(void* const* d_in, const int* in_sizes, int n_in,
                              void* d_out, int out_size, void* d_ws, size_t ws_size,
                              hipStream_t stream) {
  const float* x    = (const float*)d_in[0];
  const float* W_in = (const float*)d_in[1];
  const float* W_out= (const float*)d_in[2];
  const float* ln1w = (const float*)d_in[3];
  const float* ln1b = (const float*)d_in[4];
  const float* ln2w = (const float*)d_in[5];
  const float* ln2b = (const float*)d_in[6];
  const float* Lre  = (const float*)d_in[7];
  const float* Lim  = (const float*)d_in[8];
  const float* lstep= (const float*)d_in[9];
  const float* Bre  = (const float*)d_in[10];
  const float* Bim  = (const float*)d_in[11];
  const float* Cre  = (const float*)d_in[12];
  const float* Cim  = (const float*)d_in[13];
  const float* Dv   = (const float*)d_in[14];
  const float* ffe  = (const float*)d_in[15];
  const float* ffd  = (const float*)d_in[16];
  float* out = (float*)d_out;
  char* ws = (char*)d_ws;

  bf16* winb   = (bf16*)(ws);
  bf16* woutb  = (bf16*)(ws + (1u << 20));
  bf16* bcat   = (bf16*)(ws + (2u << 20));
  bf16* ccomb  = (bf16*)(ws + (4u << 20));
  bf16* ffeb   = (bf16*)(ws + (8u << 20));
  bf16* ffdb   = (bf16*)(ws + (12u << 20));
  float2* lamb = (float2*)(ws + (14u << 20));
  float2* coef = (float2*)(ws + (14u << 20) + 8192);
  bf16* E      = (bf16*)(ws + (16u << 20));        // 32MB bf16 slot
  float2* carry = (float2*)(ws + (16u << 20));     // overlaps E (lifetimes disjoint)
  float2* seed  = (float2*)(ws + (24u << 20));
  float* Abuf  = (float*)(ws + (48u << 20));       // 64MB
  float* Bbuf  = (float*)(ws + (112u << 20));      // 64MB
  float* Cbuf  = (float*)(ws + (176u << 20));      // 64MB: xs, later a_b|G
  bf16* xsb    = (bf16*)Cbuf;
  bf16* a_b    = (bf16*)Cbuf;                      // 32MB (after xs dead)
  bf16* G      = ((bf16*)Cbuf) + 16777216;         // 32MB

  // prep
  k_prep<<<2, 256, 0, stream>>>(Lre, Lim, lstep, lamb, coef);
  k_f32_to_bf16<<<512, 256, 0, stream>>>(W_in, winb, 524288);
  k_f32_to_bf16<<<512, 256, 0, stream>>>(W_out, woutb, 524288);
  k_f32_to_bf16<<<2048, 256, 0, stream>>>(ffe, ffeb, 2097152);
  k_f32_to_bf16<<<1024, 256, 0, stream>>>(ffd, ffdb, 1048576);
  k_f32_to_bf16<<<8192, 256, 0, stream>>>(x, E, 8388608);  // x_b
  k_bcat<<<2048, 256, 0, stream>>>(Bre, Bim, coef, bcat);
  k_ccomb<<<8192, 256, 0, stream>>>(Cre, Cim, ccomb);

  // h = x @ W_in^T -> Abuf
  k_gemm<0><<<1024, 256, 0, stream>>>(E, winb, Abuf, nullptr, nullptr, nullptr, 512, 1024, 3);
  // fx = LN1(h) -> Bbuf(f32), E(bf16)
  k_ln<<<16384, 256, 0, stream>>>(Abuf, ln1w, ln1b, Bbuf, E);
  // Bu = fx @ Bcat^T -> Abuf
  k_gemm<0><<<1024, 256, 0, stream>>>(E, bcat, Abuf, nullptr, nullptr, nullptr, 1024, 1024, 3);
  // xs -> Cbuf (bf16) via 3-pass chunked scan
  k_scanA<<<4 * NC, 256, 0, stream>>>(Abuf, lamb, carry);
  k_scanB<<<4, 256, 0, stream>>>(carry, lamb, seed);
  k_scanC<<<4 * NC, 256, 0, stream>>>(Abuf, lamb, seed, xsb);
  // ys = xs @ Ccomb^T -> Abuf
  k_gemm<0><<<1024, 256, 0, stream>>>(xsb, ccomb, Abuf, nullptr, nullptr, nullptr, 2048, 1024, 3);
  // x2 = gelu(ys + D*fx) + fx; fx2 = LN2(x2) -> Bbuf (in place), E (bf16)
  k_ln2e<<<16384, 256, 0, stream>>>(Abuf, Bbuf, Dv, ln2w, ln2b, Bbuf, E);
  // a-half -> a_b (bf16)
  k_gemm<3><<<1024, 256, 0, stream>>>(E, ffeb, nullptr, a_b, nullptr, nullptr, 1024, 1024, 3);
  // g-half + fused geglu -> G (bf16)
  k_gemm<1><<<1024, 256, 0, stream>>>(E, ffeb + (size_t)1024 * 1024, nullptr, G, nullptr, a_b, 1024, 1024, 3);
  // ffo + residual -> E (bf16)
  k_gemm<2><<<1024, 256, 0, stream>>>(G, ffdb, nullptr, E, Bbuf, nullptr, 1024, 1024, 3);
  // out = x3 @ W_out^T
  k_gemm<0><<<512, 256, 0, stream>>>(E, woutb, out, nullptr, nullptr, nullptr, 1024, 512, 2);
}

// Round 4
// 546.954 us; speedup vs baseline: 1.6507x; 1.0765x over previous
//
#include <hip/hip_runtime.h>
#include <cstdint>

typedef __bf16 bf16;
typedef __bf16 bf16x2 __attribute__((ext_vector_type(2)));
typedef __bf16 bf16x4 __attribute__((ext_vector_type(4)));
typedef __bf16 bf16x8 __attribute__((ext_vector_type(8)));
typedef float f32x4 __attribute__((ext_vector_type(4)));

#define MROWS 16384
#define DIMH 1024
#define PDIM 512
#define LSEQ 4096
#define CL 16
#define NC (LSEQ / CL)  // 256

typedef const __attribute__((address_space(1))) unsigned int* gas_t;
typedef __attribute__((address_space(3))) unsigned int* las_t;

__device__ __forceinline__ float gelu_f(float x) {
  return 0.5f * x * (1.0f + erff(x * 0.70710678118654752f));
}

// ---------------------------------------------------------------- small prep
__global__ void k_prep(const float* __restrict__ Lre, const float* __restrict__ Lim,
                       const float* __restrict__ lstep,
                       float2* __restrict__ lamb, float2* __restrict__ coef) {
  const int p = blockIdx.x * blockDim.x + threadIdx.x;
  if (p >= PDIM) return;
  const float lre = Lre[p], lim = Lim[p];
  const float st = expf(lstep[p]);
  const float er = expf(lre * st);
  const float lbr = er * cosf(lim * st);
  const float lbi = er * sinf(lim * st);
  lamb[p] = make_float2(lbr, lbi);
  const float ar = lbr - 1.0f, ai = lbi;
  const float d = lre * lre + lim * lim;
  coef[p] = make_float2((ar * lre + ai * lim) / d, (ai * lre - ar * lim) / d);
}

__global__ void k_f32_to_bf16(const float* __restrict__ in, bf16* __restrict__ outp, int n) {
  const int i = (blockIdx.x * 256 + threadIdx.x) * 4;
  if (i >= n) return;
  const float4 v = *(const float4*)(in + i);
  bf16x4 o = { (bf16)v.x, (bf16)v.y, (bf16)v.z, (bf16)v.w };
  *(bf16x4*)(outp + i) = o;
}

// bcat: rows 0..511 = Re(B_bar), rows 512..1023 = Im(B_bar)
__global__ void k_bcat(const float* __restrict__ Bre, const float* __restrict__ Bim,
                       const float2* __restrict__ coef, bf16* __restrict__ bcat) {
  const int idx = blockIdx.x * 256 + threadIdx.x;  // 512*1024
  const int p = idx >> 10;
  const float2 c = coef[p];
  const float br = Bre[idx], bi = Bim[idx];
  bcat[idx] = (bf16)(c.x * br - c.y * bi);
  bcat[idx + PDIM * DIMH] = (bf16)(c.x * bi + c.y * br);
}

// ccomb[n][k], k-layout [xsf_re | xsf_im | xsb_re | xsb_im]
__global__ void k_ccomb(const float* __restrict__ Cre, const float* __restrict__ Cim,
                        bf16* __restrict__ cc) {
  const int idx = blockIdx.x * 256 + threadIdx.x;  // 1024*2048
  const int n = idx >> 11, k = idx & 2047;
  float v;
  if (k < 512)       v =  2.0f * Cre[n * 1024 + k];
  else if (k < 1024) v = -2.0f * Cim[n * 1024 + (k - 512)];
  else if (k < 1536) v =  2.0f * Cre[n * 1024 + 512 + (k - 1024)];
  else               v = -2.0f * Cim[n * 1024 + 512 + (k - 1536)];
  cc[idx] = (bf16)v;
}

// ---------------------------------------------------------------- GEMM
// C[M,N] = A[M,K] bf16 @ W[N,K]^T bf16.  128x128 tile, BK=64, 4 waves,
// global_load_lds width-16 staging + XCD swizzle + 16B-chunk XOR LDS swizzle
// (both-sides: pre-swizzled global source, swizzled ds_read).
// EPI: 0 = f32 store; 1 = bf16( auxb * gelu(acc) ); 2 = bf16( acc + auxf );
//      3 = bf16 store.
#define BM 128
#define BN 128
#define BK 64

template <int EPI>
__global__ __launch_bounds__(256) void k_gemm(const bf16* __restrict__ A,
                                              const bf16* __restrict__ W,
                                              float* __restrict__ Cf,
                                              bf16* __restrict__ Cb,
                                              const float* __restrict__ auxf,
                                              const bf16* __restrict__ auxb,
                                              int K, int N, int nbnl) {
  // bijective XCD swizzle (nwg divisible by 8): each XCD gets contiguous rows
  const int q = gridDim.x >> 3;
  const int s = (blockIdx.x & 7) * q + (blockIdx.x >> 3);
  const int bm = s >> nbnl;
  const int bn = s & ((1 << nbnl) - 1);
  const int tid = threadIdx.x;
  const int lane = tid & 63;
  const int wave = tid >> 6;
  const int wr = wave >> 1, wc = wave & 1;
  __shared__ bf16 As[BM][BK];
  __shared__ bf16 Ws[BN][BK];
  f32x4 acc[4][4];
#pragma unroll
  for (int i = 0; i < 4; ++i)
#pragma unroll
    for (int j = 0; j < 4; ++j) acc[i][j] = (f32x4){0.f, 0.f, 0.f, 0.f};

  const size_t arow = (size_t)bm * BM;
  const size_t wrow = (size_t)bn * BN;
  const int srow = lane >> 3;                       // 0..7 (row within 8-row stripe)
  const int scol_sw = (((lane & 7) ^ srow) << 3);   // pre-swizzled source chunk

  for (int k0 = 0; k0 < K; k0 += BK) {
#pragma unroll
    for (int it = 0; it < 4; ++it) {
      const int rbase = (it * 4 + wave) * 8;
      __builtin_amdgcn_global_load_lds(
          (gas_t)(A + (arow + rbase + srow) * (size_t)K + k0 + scol_sw),
          (las_t)(&As[rbase][0]), 16, 0, 0);
      __builtin_amdgcn_global_load_lds(
          (gas_t)(W + (wrow + rbase + srow) * (size_t)K + k0 + scol_sw),
          (las_t)(&Ws[rbase][0]), 16, 0, 0);
    }
    __syncthreads();
    const int lrow = lane & 15;
    const int r7 = lane & 7;
#pragma unroll
    for (int kk = 0; kk < BK; kk += 32) {
      const int lc = (kk >> 3) + (lane >> 4);       // logical 16B chunk 0..7
      const int pc = ((lc ^ r7) << 3);              // physical element offset
      bf16x8 af[4], wf[4];
#pragma unroll
      for (int i = 0; i < 4; ++i) af[i] = *(const bf16x8*)(&As[wr * 64 + i * 16 + lrow][pc]);
#pragma unroll
      for (int j = 0; j < 4; ++j) wf[j] = *(const bf16x8*)(&Ws[wc * 64 + j * 16 + lrow][pc]);
#pragma unroll
      for (int i = 0; i < 4; ++i)
#pragma unroll
        for (int j = 0; j < 4; ++j)
          acc[i][j] = __builtin_amdgcn_mfma_f32_16x16x32_bf16(af[i], wf[j], acc[i][j], 0, 0, 0);
    }
    __syncthreads();
  }
  // D layout: col = lane&15, row = (lane>>4)*4 + reg
  const int n0 = (int)wrow + wc * 64 + (lane & 15);
  const size_t m0 = arow + wr * 64 + ((lane >> 4) << 2);
#pragma unroll
  for (int i = 0; i < 4; ++i)
#pragma unroll
    for (int j = 0; j < 4; ++j) {
      const size_t mb = m0 + i * 16;
      const int n = n0 + j * 16;
#pragma unroll
      for (int r = 0; r < 4; ++r) {
        const size_t idx = (mb + r) * (size_t)N + n;
        const float v = acc[i][j][r];
        if constexpr (EPI == 0) {
          Cf[idx] = v;
        } else if constexpr (EPI == 1) {
          Cb[idx] = (bf16)((float)auxb[idx] * gelu_f(v));
        } else if constexpr (EPI == 2) {
          Cb[idx] = (bf16)(v + auxf[idx]);
        } else {
          Cb[idx] = (bf16)v;
        }
      }
    }
}

// ---------------------------------------------------------------- LayerNorm
__global__ __launch_bounds__(256) void k_ln(const float* __restrict__ X,
                                            const float* __restrict__ w,
                                            const float* __restrict__ bb,
                                            float* __restrict__ Yf, bf16* __restrict__ Yb) {
  const int m = blockIdx.x;
  const int tid = threadIdx.x;
  const float4 v = ((const float4*)(X + (size_t)m * DIMH))[tid];
  float s = v.x + v.y + v.z + v.w;
  float s2 = v.x * v.x + v.y * v.y + v.z * v.z + v.w * v.w;
#pragma unroll
  for (int off = 32; off > 0; off >>= 1) { s += __shfl_down(s, off); s2 += __shfl_down(s2, off); }
  __shared__ float rs[4], rq[4];
  if ((tid & 63) == 0) { rs[tid >> 6] = s; rq[tid >> 6] = s2; }
  __syncthreads();
  s = rs[0] + rs[1] + rs[2] + rs[3];
  s2 = rq[0] + rq[1] + rq[2] + rq[3];
  const float mu = s * (1.0f / DIMH);
  const float inv = rsqrtf(s2 * (1.0f / DIMH) - mu * mu + 1e-5f);
  const float4 wv = ((const float4*)w)[tid];
  const float4 bv = ((const float4*)bb)[tid];
  const float o0 = (v.x - mu) * inv * wv.x + bv.x;
  const float o1 = (v.y - mu) * inv * wv.y + bv.y;
  const float o2 = (v.z - mu) * inv * wv.z + bv.z;
  const float o3 = (v.w - mu) * inv * wv.w + bv.w;
  ((float4*)(Yf + (size_t)m * DIMH))[tid] = make_float4(o0, o1, o2, o3);
  bf16x4 ob = { (bf16)o0, (bf16)o1, (bf16)o2, (bf16)o3 };
  *(bf16x4*)(Yb + (size_t)m * DIMH + tid * 4) = ob;
}

// fused: t = gelu(ys + D*fx) + fx ; LN(t) -> Yf (aliases FX), Yb
__global__ __launch_bounds__(256) void k_ln2e(const float* __restrict__ YS,
                                              const float* __restrict__ FX,
                                              const float* __restrict__ Dv,
                                              const float* __restrict__ w,
                                              const float* __restrict__ bb,
                                              float* __restrict__ Yf, bf16* __restrict__ Yb) {
  const int m = blockIdx.x;
  const int tid = threadIdx.x;
  const float4 ys = ((const float4*)(YS + (size_t)m * DIMH))[tid];
  const float4 fx = ((const float4*)(FX + (size_t)m * DIMH))[tid];
  const float4 dv = ((const float4*)Dv)[tid];
  const float t0 = gelu_f(ys.x + dv.x * fx.x) + fx.x;
  const float t1 = gelu_f(ys.y + dv.y * fx.y) + fx.y;
  const float t2 = gelu_f(ys.z + dv.z * fx.z) + fx.z;
  const float t3 = gelu_f(ys.w + dv.w * fx.w) + fx.w;
  float s = t0 + t1 + t2 + t3;
  float s2 = t0 * t0 + t1 * t1 + t2 * t2 + t3 * t3;
#pragma unroll
  for (int off = 32; off > 0; off >>= 1) { s += __shfl_down(s, off); s2 += __shfl_down(s2, off); }
  __shared__ float rs[4], rq[4];
  if ((tid & 63) == 0) { rs[tid >> 6] = s; rq[tid >> 6] = s2; }
  __syncthreads();
  s = rs[0] + rs[1] + rs[2] + rs[3];
  s2 = rq[0] + rq[1] + rq[2] + rq[3];
  const float mu = s * (1.0f / DIMH);
  const float inv = rsqrtf(s2 * (1.0f / DIMH) - mu * mu + 1e-5f);
  const float4 wv = ((const float4*)w)[tid];
  const float4 bv = ((const float4*)bb)[tid];
  const float o0 = (t0 - mu) * inv * wv.x + bv.x;
  const float o1 = (t1 - mu) * inv * wv.y + bv.y;
  const float o2 = (t2 - mu) * inv * wv.z + bv.z;
  const float o3 = (t3 - mu) * inv * wv.w + bv.w;
  ((float4*)(Yf + (size_t)m * DIMH))[tid] = make_float4(o0, o1, o2, o3);
  bf16x4 ob = { (bf16)o0, (bf16)o1, (bf16)o2, (bf16)o3 };
  *(bf16x4*)(Yb + (size_t)m * DIMH + tid * 4) = ob;
}

// ---------------------------------------------------------------- scan (3-pass)
__global__ __launch_bounds__(256) void k_scanA(const float* __restrict__ Bu,
                                               const float2* __restrict__ lamb,
                                               float2* __restrict__ carry) {
  const int bc = blockIdx.x;
  const int b = bc >> 8, c = bc & (NC - 1);
  const int t = threadIdx.x;
  const size_t rbase = ((size_t)b * LSEQ + (size_t)c * CL) * DIMH;
  float2 re[CL], im[CL];
#pragma unroll
  for (int i = 0; i < CL; ++i) {
    re[i] = *(const float2*)(Bu + rbase + (size_t)i * DIMH + 2 * t);
    im[i] = *(const float2*)(Bu + rbase + (size_t)i * DIMH + PDIM + 2 * t);
  }
  const float2 l0 = lamb[2 * t];
  const float2 l1 = lamb[2 * t + 1];
  const size_t cb = ((size_t)bc * 2) * PDIM;
  {
    float s0r = 0.f, s0i = 0.f, s1r = 0.f, s1i = 0.f;
#pragma unroll
    for (int i = 0; i < CL; ++i) {
      float nr = l0.x * s0r - l0.y * s0i + re[i].x;
      float ni = l0.x * s0i + l0.y * s0r + im[i].x;
      s0r = nr; s0i = ni;
      nr = l1.x * s1r - l1.y * s1i + re[i].y;
      ni = l1.x * s1i + l1.y * s1r + im[i].y;
      s1r = nr; s1i = ni;
    }
    carry[cb + 2 * t]     = make_float2(s0r, s0i);
    carry[cb + 2 * t + 1] = make_float2(s1r, s1i);
  }
  {
    float s0r = 0.f, s0i = 0.f, s1r = 0.f, s1i = 0.f;
#pragma unroll
    for (int i = CL - 1; i >= 0; --i) {
      float nr = l0.x * s0r - l0.y * s0i + re[i].x;
      float ni = l0.x * s0i + l0.y * s0r + im[i].x;
      s0r = nr; s0i = ni;
      nr = l1.x * s1r - l1.y * s1i + re[i].y;
      ni = l1.x * s1i + l1.y * s1r + im[i].y;
      s1r = nr; s1i = ni;
    }
    carry[cb + PDIM + 2 * t]     = make_float2(s0r, s0i);
    carry[cb + PDIM + 2 * t + 1] = make_float2(s1r, s1i);
  }
}

__global__ __launch_bounds__(256) void k_scanB(const float2* __restrict__ carry,
                                               const float2* __restrict__ lamb,
                                               float2* __restrict__ seed) {
  const int b = blockIdx.x;  // 4 blocks
  const int t = threadIdx.x;
  const float2 l0 = lamb[2 * t], l1 = lamb[2 * t + 1];
  float L0r = l0.x, L0i = l0.y, L1r = l1.x, L1i = l1.y;
#pragma unroll
  for (int q = 0; q < 4; ++q) {
    float tr = L0r * L0r - L0i * L0i; L0i = 2.f * L0r * L0i; L0r = tr;
    tr = L1r * L1r - L1i * L1i; L1i = 2.f * L1r * L1i; L1r = tr;
  }
  float S0r = 0.f, S0i = 0.f, S1r = 0.f, S1i = 0.f;
  for (int c = 0; c < NC; ++c) {
    const size_t base = (((size_t)b * NC + c) * 2) * PDIM;
    const float2 c0 = carry[base + 2 * t];
    const float2 c1 = carry[base + 2 * t + 1];
    seed[base + 2 * t]     = make_float2(S0r, S0i);
    seed[base + 2 * t + 1] = make_float2(S1r, S1i);
    float nr = L0r * S0r - L0i * S0i + c0.x;
    float ni = L0r * S0i + L0i * S0r + c0.y;
    S0r = nr; S0i = ni;
    nr = L1r * S1r - L1i * S1i + c1.x;
    ni = L1r * S1i + L1i * S1r + c1.y;
    S1r = nr; S1i = ni;
  }
  S0r = 0.f; S0i = 0.f; S1r = 0.f; S1i = 0.f;
  for (int c = NC - 1; c >= 0; --c) {
    const size_t base = (((size_t)b * NC + c) * 2) * PDIM + PDIM;
    const float2 c0 = carry[base + 2 * t];
    const float2 c1 = carry[base + 2 * t + 1];
    seed[base + 2 * t]     = make_float2(S0r, S0i);
    seed[base + 2 * t + 1] = make_float2(S1r, S1i);
    float nr = L0r * S0r - L0i * S0i + c0.x;
    float ni = L0r * S0i + L0i * S0r + c0.y;
    S0r = nr; S0i = ni;
    nr = L1r * S1r - L1i * S1i + c1.x;
    ni = L1r * S1i + L1i * S1r + c1.y;
    S1r = nr; S1i = ni;
  }
}

__global__ __launch_bounds__(256) void k_scanC(const float* __restrict__ Bu,
                                               const float2* __restrict__ lamb,
                                               const float2* __restrict__ seed,
                                               bf16* __restrict__ xs) {
  const int bc = blockIdx.x;
  const int b = bc >> 8, c = bc & (NC - 1);
  const int t = threadIdx.x;
  const size_t rbase = ((size_t)b * LSEQ + (size_t)c * CL) * DIMH;
  float2 re[CL], im[CL];
#pragma unroll
  for (int i = 0; i < CL; ++i) {
    re[i] = *(const float2*)(Bu + rbase + (size_t)i * DIMH + 2 * t);
    im[i] = *(const float2*)(Bu + rbase + (size_t)i * DIMH + PDIM + 2 * t);
  }
  const float2 l0 = lamb[2 * t];
  const float2 l1 = lamb[2 * t + 1];
  const size_t sb = ((size_t)bc * 2) * PDIM;
  const size_t obase = ((size_t)b * LSEQ + (size_t)c * CL) * 2048;
  {
    const float2 s0 = seed[sb + 2 * t];
    const float2 s1 = seed[sb + 2 * t + 1];
    float s0r = s0.x, s0i = s0.y, s1r = s1.x, s1i = s1.y;
#pragma unroll
    for (int i = 0; i < CL; ++i) {
      float nr = l0.x * s0r - l0.y * s0i + re[i].x;
      float ni = l0.x * s0i + l0.y * s0r + im[i].x;
      s0r = nr; s0i = ni;
      nr = l1.x * s1r - l1.y * s1i + re[i].y;
      ni = l1.x * s1i + l1.y * s1r + im[i].y;
      s1r = nr; s1i = ni;
      bf16x2 wr2 = { (bf16)s0r, (bf16)s1r };
      bf16x2 wi2 = { (bf16)s0i, (bf16)s1i };
      *(bf16x2*)(xs + obase + (size_t)i * 2048 + 2 * t) = wr2;
      *(bf16x2*)(xs + obase + (size_t)i * 2048 + PDIM + 2 * t) = wi2;
    }
  }
  {
    const float2 s0 = seed[sb + PDIM + 2 * t];
    const float2 s1 = seed[sb + PDIM + 2 * t + 1];
    float s0r = s0.x, s0i = s0.y, s1r = s1.x, s1i = s1.y;
#pragma unroll
    for (int i = CL - 1; i >= 0; --i) {
      float nr = l0.x * s0r - l0.y * s0i + re[i].x;
      float ni = l0.x * s0i + l0.y * s0r + im[i].x;
      s0r = nr; s0i = ni;
      nr = l1.x * s1r - l1.y * s1i + re[i].y;
      ni = l1.x * s1i + l1.y * s1r + im[i].y;
      s1r = nr; s1i = ni;
      bf16x2 wr2 = { (bf16)s0r, (bf16)s1r };
      bf16x2 wi2 = { (bf16)s0i, (bf16)s1i };
      *(bf16x2*)(xs + obase + (size_t)i * 2048 + 1024 + 2 * t) = wr2;
      *(bf16x2*)(xs + obase + (size_t)i * 2048 + 1536 + 2 * t) = wi2;
    }
  }
}

// ---------------------------------------------------------------- launch
extern "C" void kernel_launch(void* const* d_in, const int* in_sizes, int n_in,
                              void* d_out, int out_size, void* d_ws, size_t ws_size,
                              hipStream_t stream) {
  const float* x    = (const float*)d_in[0];
  const float* W_in = (const float*)d_in[1];
  const float* W_out= (const float*)d_in[2];
  const float* ln1w = (const float*)d_in[3];
  const float* ln1b = (const float*)d_in[4];
  const float* ln2w = (const float*)d_in[5];
  const float* ln2b = (const float*)d_in[6];
  const float* Lre  = (const float*)d_in[7];
  const float* Lim  = (const float*)d_in[8];
  const float* lstep= (const float*)d_in[9];
  const float* Bre  = (const float*)d_in[10];
  const float* Bim  = (const float*)d_in[11];
  const float* Cre  = (const float*)d_in[12];
  const float* Cim  = (const float*)d_in[13];
  const float* Dv   = (const float*)d_in[14];
  const float* ffe  = (const float*)d_in[15];
  const float* ffd  = (const float*)d_in[16];
  float* out = (float*)d_out;
  char* ws = (char*)d_ws;

  bf16* winb   = (bf16*)(ws);
  bf16* woutb  = (bf16*)(ws + (1u << 20));
  bf16* bcat   = (bf16*)(ws + (2u << 20));
  bf16* ccomb  = (bf16*)(ws + (4u << 20));
  bf16* ffeb   = (bf16*)(ws + (8u << 20));
  bf16* ffdb   = (bf16*)(ws + (12u << 20));
  float2* lamb = (float2*)(ws + (14u << 20));
  float2* coef = (float2*)(ws + (14u << 20) + 8192);
  bf16* E      = (bf16*)(ws + (16u << 20));        // 32MB bf16 slot
  float2* carry = (float2*)(ws + (16u << 20));     // overlaps E (lifetimes disjoint)
  float2* seed  = (float2*)(ws + (24u << 20));
  float* Abuf  = (float*)(ws + (48u << 20));       // 64MB
  float* Bbuf  = (float*)(ws + (112u << 20));      // 64MB
  float* Cbuf  = (float*)(ws + (176u << 20));      // 64MB: xs, later a_b|G
  bf16* xsb    = (bf16*)Cbuf;
  bf16* a_b    = (bf16*)Cbuf;                      // 32MB (after xs dead)
  bf16* G      = ((bf16*)Cbuf) + 16777216;         // 32MB

  // prep
  k_prep<<<2, 256, 0, stream>>>(Lre, Lim, lstep, lamb, coef);
  k_f32_to_bf16<<<512, 256, 0, stream>>>(W_in, winb, 524288);
  k_f32_to_bf16<<<512, 256, 0, stream>>>(W_out, woutb, 524288);
  k_f32_to_bf16<<<2048, 256, 0, stream>>>(ffe, ffeb, 2097152);
  k_f32_to_bf16<<<1024, 256, 0, stream>>>(ffd, ffdb, 1048576);
  k_f32_to_bf16<<<8192, 256, 0, stream>>>(x, E, 8388608);  // x_b
  k_bcat<<<2048, 256, 0, stream>>>(Bre, Bim, coef, bcat);
  k_ccomb<<<8192, 256, 0, stream>>>(Cre, Cim, ccomb);

  // h = x @ W_in^T -> Abuf
  k_gemm<0><<<1024, 256, 0, stream>>>(E, winb, Abuf, nullptr, nullptr, nullptr, 512, 1024, 3);
  // fx = LN1(h) -> Bbuf(f32), E(bf16)
  k_ln<<<16384, 256, 0, stream>>>(Abuf, ln1w, ln1b, Bbuf, E);
  // Bu = fx @ Bcat^T -> Abuf
  k_gemm<0><<<1024, 256, 0, stream>>>(E, bcat, Abuf, nullptr, nullptr, nullptr, 1024, 1024, 3);
  // xs -> Cbuf (bf16) via 3-pass chunked scan
  k_scanA<<<4 * NC, 256, 0, stream>>>(Abuf, lamb, carry);
  k_scanB<<<4, 256, 0, stream>>>(carry, lamb, seed);
  k_scanC<<<4 * NC, 256, 0, stream>>>(Abuf, lamb, seed, xsb);
  // ys = xs @ Ccomb^T -> Abuf
  k_gemm<0><<<1024, 256, 0, stream>>>(xsb, ccomb, Abuf, nullptr, nullptr, nullptr, 2048, 1024, 3);
  // x2 = gelu(ys + D*fx) + fx; fx2 = LN2(x2) -> Bbuf (in place), E (bf16)
  k_ln2e<<<16384, 256, 0, stream>>>(Abuf, Bbuf, Dv, ln2w, ln2b, Bbuf, E);
  // a-half -> a_b (bf16)
  k_gemm<3><<<1024, 256, 0, stream>>>(E, ffeb, nullptr, a_b, nullptr, nullptr, 1024, 1024, 3);
  // g-half + fused geglu -> G (bf16)
  k_gemm<1><<<1024, 256, 0, stream>>>(E, ffeb + (size_t)1024 * 1024, nullptr, G, nullptr, a_b, 1024, 1024, 3);
  // ffo + residual -> E (bf16)
  k_gemm<2><<<1024, 256, 0, stream>>>(G, ffdb, nullptr, E, Bbuf, nullptr, 1024, 1024, 3);
  // out = x3 @ W_out^T
  k_gemm<0><<<512, 256, 0, stream>>>(E, woutb, out, nullptr, nullptr, nullptr, 1024, 512, 2);
}

// Round 5
// 519.055 us; speedup vs baseline: 1.7395x; 1.0537x over previous
//
#include <hip/hip_runtime.h>
#include <cstdint>

typedef __bf16 bf16;
typedef __bf16 bf16x2 __attribute__((ext_vector_type(2)));
typedef __bf16 bf16x4 __attribute__((ext_vector_type(4)));
typedef __bf16 bf16x8 __attribute__((ext_vector_type(8)));
typedef float f32x4 __attribute__((ext_vector_type(4)));

#define MROWS 16384
#define DIMH 1024
#define PDIM 512
#define LSEQ 4096
#define CL 16
#define NC (LSEQ / CL)  // 256

typedef const __attribute__((address_space(1))) unsigned int* gas_t;
typedef __attribute__((address_space(3))) unsigned int* las_t;

__device__ __forceinline__ float gelu_f(float x) {
  return 0.5f * x * (1.0f + erff(x * 0.70710678118654752f));
}

// ---------------------------------------------------------------- small prep
__global__ void k_prep(const float* __restrict__ Lre, const float* __restrict__ Lim,
                       const float* __restrict__ lstep,
                       float2* __restrict__ lamb, float2* __restrict__ coef) {
  const int p = blockIdx.x * blockDim.x + threadIdx.x;
  if (p >= PDIM) return;
  const float lre = Lre[p], lim = Lim[p];
  const float st = expf(lstep[p]);
  const float er = expf(lre * st);
  const float lbr = er * cosf(lim * st);
  const float lbi = er * sinf(lim * st);
  lamb[p] = make_float2(lbr, lbi);
  const float ar = lbr - 1.0f, ai = lbi;
  const float d = lre * lre + lim * lim;
  coef[p] = make_float2((ar * lre + ai * lim) / d, (ai * lre - ar * lim) / d);
}

__global__ void k_f32_to_bf16(const float* __restrict__ in, bf16* __restrict__ outp, int n) {
  const int i = (blockIdx.x * 256 + threadIdx.x) * 4;
  if (i >= n) return;
  const float4 v = *(const float4*)(in + i);
  bf16x4 o = { (bf16)v.x, (bf16)v.y, (bf16)v.z, (bf16)v.w };
  *(bf16x4*)(outp + i) = o;
}

// bcat: rows 0..511 = Re(B_bar), rows 512..1023 = Im(B_bar)
__global__ void k_bcat(const float* __restrict__ Bre, const float* __restrict__ Bim,
                       const float2* __restrict__ coef, bf16* __restrict__ bcat) {
  const int idx = blockIdx.x * 256 + threadIdx.x;  // 512*1024
  const int p = idx >> 10;
  const float2 c = coef[p];
  const float br = Bre[idx], bi = Bim[idx];
  bcat[idx] = (bf16)(c.x * br - c.y * bi);
  bcat[idx + PDIM * DIMH] = (bf16)(c.x * bi + c.y * br);
}

// ccomb[n][k], k-layout [xsf_re | xsf_im | xsb_re | xsb_im]
__global__ void k_ccomb(const float* __restrict__ Cre, const float* __restrict__ Cim,
                        bf16* __restrict__ cc) {
  const int idx = blockIdx.x * 256 + threadIdx.x;  // 1024*2048
  const int n = idx >> 11, k = idx & 2047;
  float v;
  if (k < 512)       v =  2.0f * Cre[n * 1024 + k];
  else if (k < 1024) v = -2.0f * Cim[n * 1024 + (k - 512)];
  else if (k < 1536) v =  2.0f * Cre[n * 1024 + 512 + (k - 1024)];
  else               v = -2.0f * Cim[n * 1024 + 512 + (k - 1536)];
  cc[idx] = (bf16)v;
}

// ---------------------------------------------------------------- GEMM (256x256, 8-phase)
// C[M,N] = A[M,K] bf16 @ W[N,K]^T bf16.  8 waves (512 thr), BK=64 per K-tile,
// 2 K-tiles per iteration, counted vmcnt(4), raw barriers, LDS 128 KiB dynamic.
// LDS layout per operand: slot(2) x kkhalf(2) x [256 rows][32 cols] bf16,
// 16B-chunk XOR swizzle pc = lc ^ ((row>>1)&3).  B at byte offset 65536.
// EPI: 0 = f32 store; 1 = bf16(auxb * gelu(acc)); 2 = bf16(acc + auxf); 3 = bf16.

#define VMCNT4 asm volatile("s_waitcnt vmcnt(4)" ::: "memory")
#define VMCNT0 asm volatile("s_waitcnt vmcnt(0)" ::: "memory")
#define LGKM0  asm volatile("s_waitcnt lgkmcnt(0)" ::: "memory")
#define SCHED0 __builtin_amdgcn_sched_barrier(0)
#define BAR    __builtin_amdgcn_s_barrier()

#define PHASE(slot, kh, mh, LOADB, STAGE_STMT, WAIT_STMT)                      \
  {                                                                            \
    if (LOADB) ldB(slot, kh, bfr);                                             \
    ldA(slot, kh, mh, afr);                                                    \
    STAGE_STMT;                                                                \
    SCHED0;                                                                    \
    BAR;                                                                       \
    LGKM0;                                                                     \
    SCHED0;                                                                    \
    __builtin_amdgcn_s_setprio(1);                                             \
    _Pragma("unroll")                                                          \
    for (int m = 0; m < 4; ++m)                                                \
      _Pragma("unroll")                                                        \
      for (int n = 0; n < 4; ++n)                                              \
        acc[(mh) * 4 + m][n] = __builtin_amdgcn_mfma_f32_16x16x32_bf16(        \
            afr[m], bfr[n], acc[(mh) * 4 + m][n], 0, 0, 0);                    \
    __builtin_amdgcn_s_setprio(0);                                             \
    SCHED0;                                                                    \
    WAIT_STMT;                                                                 \
    BAR;                                                                       \
  }

template <int EPI>
__global__ __launch_bounds__(512, 2) void k_gemm(const bf16* __restrict__ A,
                                                 const bf16* __restrict__ W,
                                                 float* __restrict__ Cf,
                                                 bf16* __restrict__ Cb,
                                                 const float* __restrict__ auxf,
                                                 const bf16* __restrict__ auxb,
                                                 int K, int N, int nbnl) {
  extern __shared__ char lds[];  // 131072 bytes
  const int q = (int)gridDim.x >> 3;
  const int s = ((int)blockIdx.x & 7) * q + ((int)blockIdx.x >> 3);
  const int bm = s >> nbnl;
  const int bn = s & ((1 << nbnl) - 1);
  const int tid = threadIdx.x;
  const int lane = tid & 63;
  const int wave = tid >> 6;
  const int wr = wave >> 2;  // 0..1
  const int wc = wave & 3;   // 0..3

  const size_t arow0 = (size_t)bm * 256;
  const size_t wrow0 = (size_t)bn * 256;
  const int srow = tid >> 2;                         // 0..127 per issue
  const int schunk = (tid & 3) ^ ((tid >> 3) & 3);   // inverse-swizzled src chunk
  const int wbase = wave << 10;                      // wave-uniform LDS sub-base

  f32x4 acc[8][4];
#pragma unroll
  for (int i = 0; i < 8; ++i)
#pragma unroll
    for (int j = 0; j < 4; ++j) acc[i][j] = (f32x4){0.f, 0.f, 0.f, 0.f};

  // stage one (slot, kkhalf) group: A(2 issues) + B(2 issues) = 4 loads/wave
  auto stage = [&](int slot, int kh, int kt) {
    const int kcol = kt * 64 + kh * 32 + schunk * 8;
    {
      char* base = lds + slot * 32768 + kh * 16384;
      __builtin_amdgcn_global_load_lds(
          (gas_t)(A + (arow0 + srow) * (size_t)K + kcol), (las_t)(base + wbase), 16, 0, 0);
      __builtin_amdgcn_global_load_lds(
          (gas_t)(A + (arow0 + 128 + srow) * (size_t)K + kcol), (las_t)(base + 8192 + wbase), 16, 0, 0);
    }
    {
      char* base = lds + 65536 + slot * 32768 + kh * 16384;
      __builtin_amdgcn_global_load_lds(
          (gas_t)(W + (wrow0 + srow) * (size_t)K + kcol), (las_t)(base + wbase), 16, 0, 0);
      __builtin_amdgcn_global_load_lds(
          (gas_t)(W + (wrow0 + 128 + srow) * (size_t)K + kcol), (las_t)(base + 8192 + wbase), 16, 0, 0);
    }
  };

  auto ldA = [&](int slot, int kh, int mh, bf16x8* af) {
#pragma unroll
    for (int m = 0; m < 4; ++m) {
      const int row = wr * 128 + mh * 64 + m * 16 + (lane & 15);
      const int pc = (lane >> 4) ^ ((row >> 1) & 3);
      af[m] = *(const bf16x8*)(lds + slot * 32768 + kh * 16384 + row * 64 + pc * 16);
    }
  };
  auto ldB = [&](int slot, int kh, bf16x8* bf) {
#pragma unroll
    for (int n = 0; n < 4; ++n) {
      const int row = wc * 64 + n * 16 + (lane & 15);
      const int pc = (lane >> 4) ^ ((row >> 1) & 3);
      bf[n] = *(const bf16x8*)(lds + 65536 + slot * 32768 + kh * 16384 + row * 64 + pc * 16);
    }
  };

  bf16x8 afr[4], bfr[4];

  // prologue: E fully (kt0), O.kk0 (kt1); complete E, leave O.kk0 in flight
  stage(0, 0, 0);
  stage(0, 1, 0);
  stage(1, 0, 1);
  VMCNT4;
  BAR;

  const int NT = K >> 7;  // K/128 iterations, 2 K-tiles each
  for (int t = 0; t < NT; ++t) {
    const int nl = (t + 1 < NT);
    PHASE(0, 0, 0, 1, stage(1, 1, 2 * t + 1), (void)0);
    PHASE(0, 0, 1, 0, (void)0, (void)0);
    PHASE(0, 1, 0, 1, if (nl) stage(0, 0, 2 * t + 2), (void)0);
    if (nl) { PHASE(0, 1, 1, 0, (void)0, VMCNT4); }
    else    { PHASE(0, 1, 1, 0, (void)0, VMCNT0); }
    PHASE(1, 0, 0, 1, if (nl) stage(0, 1, 2 * t + 2), (void)0);
    PHASE(1, 0, 1, 0, (void)0, (void)0);
    PHASE(1, 1, 0, 1, if (nl) stage(1, 0, 2 * t + 3), (void)0);
    if (nl) { PHASE(1, 1, 1, 0, (void)0, VMCNT4); }
    else    { PHASE(1, 1, 1, 0, (void)0, (void)0); }
  }

  // epilogue: C-quadrant write.  col = lane&15 dir, row = (lane>>4)*4 + r
  const int n0 = (int)wrow0 + wc * 64 + (lane & 15);
  const size_t m0 = arow0 + wr * 128 + ((lane >> 4) << 2);
#pragma unroll
  for (int mi = 0; mi < 8; ++mi)
#pragma unroll
    for (int n = 0; n < 4; ++n) {
      const size_t mb = m0 + mi * 16;
      const int nn = n0 + n * 16;
#pragma unroll
      for (int r = 0; r < 4; ++r) {
        const size_t idx = (mb + r) * (size_t)N + nn;
        const float v = acc[mi][n][r];
        if constexpr (EPI == 0) {
          Cf[idx] = v;
        } else if constexpr (EPI == 1) {
          Cb[idx] = (bf16)((float)auxb[idx] * gelu_f(v));
        } else if constexpr (EPI == 2) {
          Cb[idx] = (bf16)(v + auxf[idx]);
        } else {
          Cb[idx] = (bf16)v;
        }
      }
    }
}

// ---------------------------------------------------------------- LayerNorm
__global__ __launch_bounds__(256) void k_ln(const float* __restrict__ X,
                                            const float* __restrict__ w,
                                            const float* __restrict__ bb,
                                            float* __restrict__ Yf, bf16* __restrict__ Yb) {
  const int m = blockIdx.x;
  const int tid = threadIdx.x;
  const float4 v = ((const float4*)(X + (size_t)m * DIMH))[tid];
  float s = v.x + v.y + v.z + v.w;
  float s2 = v.x * v.x + v.y * v.y + v.z * v.z + v.w * v.w;
#pragma unroll
  for (int off = 32; off > 0; off >>= 1) { s += __shfl_down(s, off); s2 += __shfl_down(s2, off); }
  __shared__ float rs[4], rq[4];
  if ((tid & 63) == 0) { rs[tid >> 6] = s; rq[tid >> 6] = s2; }
  __syncthreads();
  s = rs[0] + rs[1] + rs[2] + rs[3];
  s2 = rq[0] + rq[1] + rq[2] + rq[3];
  const float mu = s * (1.0f / DIMH);
  const float inv = rsqrtf(s2 * (1.0f / DIMH) - mu * mu + 1e-5f);
  const float4 wv = ((const float4*)w)[tid];
  const float4 bv = ((const float4*)bb)[tid];
  const float o0 = (v.x - mu) * inv * wv.x + bv.x;
  const float o1 = (v.y - mu) * inv * wv.y + bv.y;
  const float o2 = (v.z - mu) * inv * wv.z + bv.z;
  const float o3 = (v.w - mu) * inv * wv.w + bv.w;
  ((float4*)(Yf + (size_t)m * DIMH))[tid] = make_float4(o0, o1, o2, o3);
  bf16x4 ob = { (bf16)o0, (bf16)o1, (bf16)o2, (bf16)o3 };
  *(bf16x4*)(Yb + (size_t)m * DIMH + tid * 4) = ob;
}

// fused: t = gelu(ys + D*fx) + fx ; LN(t) -> Yf (aliases FX), Yb
__global__ __launch_bounds__(256) void k_ln2e(const float* __restrict__ YS,
                                              const float* __restrict__ FX,
                                              const float* __restrict__ Dv,
                                              const float* __restrict__ w,
                                              const float* __restrict__ bb,
                                              float* __restrict__ Yf, bf16* __restrict__ Yb) {
  const int m = blockIdx.x;
  const int tid = threadIdx.x;
  const float4 ys = ((const float4*)(YS + (size_t)m * DIMH))[tid];
  const float4 fx = ((const float4*)(FX + (size_t)m * DIMH))[tid];
  const float4 dv = ((const float4*)Dv)[tid];
  const float t0 = gelu_f(ys.x + dv.x * fx.x) + fx.x;
  const float t1 = gelu_f(ys.y + dv.y * fx.y) + fx.y;
  const float t2 = gelu_f(ys.z + dv.z * fx.z) + fx.z;
  const float t3 = gelu_f(ys.w + dv.w * fx.w) + fx.w;
  float s = t0 + t1 + t2 + t3;
  float s2 = t0 * t0 + t1 * t1 + t2 * t2 + t3 * t3;
#pragma unroll
  for (int off = 32; off > 0; off >>= 1) { s += __shfl_down(s, off); s2 += __shfl_down(s2, off); }
  __shared__ float rs[4], rq[4];
  if ((tid & 63) == 0) { rs[tid >> 6] = s; rq[tid >> 6] = s2; }
  __syncthreads();
  s = rs[0] + rs[1] + rs[2] + rs[3];
  s2 = rq[0] + rq[1] + rq[2] + rq[3];
  const float mu = s * (1.0f / DIMH);
  const float inv = rsqrtf(s2 * (1.0f / DIMH) - mu * mu + 1e-5f);
  const float4 wv = ((const float4*)w)[tid];
  const float4 bv = ((const float4*)bb)[tid];
  const float o0 = (t0 - mu) * inv * wv.x + bv.x;
  const float o1 = (t1 - mu) * inv * wv.y + bv.y;
  const float o2 = (t2 - mu) * inv * wv.z + bv.z;
  const float o3 = (t3 - mu) * inv * wv.w + bv.w;
  ((float4*)(Yf + (size_t)m * DIMH))[tid] = make_float4(o0, o1, o2, o3);
  bf16x4 ob = { (bf16)o0, (bf16)o1, (bf16)o2, (bf16)o3 };
  *(bf16x4*)(Yb + (size_t)m * DIMH + tid * 4) = ob;
}

// ---------------------------------------------------------------- scan (3-pass)
__global__ __launch_bounds__(256) void k_scanA(const float* __restrict__ Bu,
                                               const float2* __restrict__ lamb,
                                               float2* __restrict__ carry) {
  const int bc = blockIdx.x;
  const int b = bc >> 8, c = bc & (NC - 1);
  const int t = threadIdx.x;
  const size_t rbase = ((size_t)b * LSEQ + (size_t)c * CL) * DIMH;
  float2 re[CL], im[CL];
#pragma unroll
  for (int i = 0; i < CL; ++i) {
    re[i] = *(const float2*)(Bu + rbase + (size_t)i * DIMH + 2 * t);
    im[i] = *(const float2*)(Bu + rbase + (size_t)i * DIMH + PDIM + 2 * t);
  }
  const float2 l0 = lamb[2 * t];
  const float2 l1 = lamb[2 * t + 1];
  const size_t cb = ((size_t)bc * 2) * PDIM;
  {
    float s0r = 0.f, s0i = 0.f, s1r = 0.f, s1i = 0.f;
#pragma unroll
    for (int i = 0; i < CL; ++i) {
      float nr = l0.x * s0r - l0.y * s0i + re[i].x;
      float ni = l0.x * s0i + l0.y * s0r + im[i].x;
      s0r = nr; s0i = ni;
      nr = l1.x * s1r - l1.y * s1i + re[i].y;
      ni = l1.x * s1i + l1.y * s1r + im[i].y;
      s1r = nr; s1i = ni;
    }
    carry[cb + 2 * t]     = make_float2(s0r, s0i);
    carry[cb + 2 * t + 1] = make_float2(s1r, s1i);
  }
  {
    float s0r = 0.f, s0i = 0.f, s1r = 0.f, s1i = 0.f;
#pragma unroll
    for (int i = CL - 1; i >= 0; --i) {
      float nr = l0.x * s0r - l0.y * s0i + re[i].x;
      float ni = l0.x * s0i + l0.y * s0r + im[i].x;
      s0r = nr; s0i = ni;
      nr = l1.x * s1r - l1.y * s1i + re[i].y;
      ni = l1.x * s1i + l1.y * s1r + im[i].y;
      s1r = nr; s1i = ni;
    }
    carry[cb + PDIM + 2 * t]     = make_float2(s0r, s0i);
    carry[cb + PDIM + 2 * t + 1] = make_float2(s1r, s1i);
  }
}

__global__ __launch_bounds__(256) void k_scanB(const float2* __restrict__ carry,
                                               const float2* __restrict__ lamb,
                                               float2* __restrict__ seed) {
  const int b = blockIdx.x;  // 4 blocks
  const int t = threadIdx.x;
  const float2 l0 = lamb[2 * t], l1 = lamb[2 * t + 1];
  float L0r = l0.x, L0i = l0.y, L1r = l1.x, L1i = l1.y;
#pragma unroll
  for (int q = 0; q < 4; ++q) {
    float tr = L0r * L0r - L0i * L0i; L0i = 2.f * L0r * L0i; L0r = tr;
    tr = L1r * L1r - L1i * L1i; L1i = 2.f * L1r * L1i; L1r = tr;
  }
  float S0r = 0.f, S0i = 0.f, S1r = 0.f, S1i = 0.f;
  for (int c = 0; c < NC; ++c) {
    const size_t base = (((size_t)b * NC + c) * 2) * PDIM;
    const float2 c0 = carry[base + 2 * t];
    const float2 c1 = carry[base + 2 * t + 1];
    seed[base + 2 * t]     = make_float2(S0r, S0i);
    seed[base + 2 * t + 1] = make_float2(S1r, S1i);
    float nr = L0r * S0r - L0i * S0i + c0.x;
    float ni = L0r * S0i + L0i * S0r + c0.y;
    S0r = nr; S0i = ni;
    nr = L1r * S1r - L1i * S1i + c1.x;
    ni = L1r * S1i + L1i * S1r + c1.y;
    S1r = nr; S1i = ni;
  }
  S0r = 0.f; S0i = 0.f; S1r = 0.f; S1i = 0.f;
  for (int c = NC - 1; c >= 0; --c) {
    const size_t base = (((size_t)b * NC + c) * 2) * PDIM + PDIM;
    const float2 c0 = carry[base + 2 * t];
    const float2 c1 = carry[base + 2 * t + 1];
    seed[base + 2 * t]     = make_float2(S0r, S0i);
    seed[base + 2 * t + 1] = make_float2(S1r, S1i);
    float nr = L0r * S0r - L0i * S0i + c0.x;
    float ni = L0r * S0i + L0i * S0r + c0.y;
    S0r = nr; S0i = ni;
    nr = L1r * S1r - L1i * S1i + c1.x;
    ni = L1r * S1i + L1i * S1r + c1.y;
    S1r = nr; S1i = ni;
  }
}

__global__ __launch_bounds__(256) void k_scanC(const float* __restrict__ Bu,
                                               const float2* __restrict__ lamb,
                                               const float2* __restrict__ seed,
                                               bf16* __restrict__ xs) {
  const int bc = blockIdx.x;
  const int b = bc >> 8, c = bc & (NC - 1);
  const int t = threadIdx.x;
  const size_t rbase = ((size_t)b * LSEQ + (size_t)c * CL) * DIMH;
  float2 re[CL], im[CL];
#pragma unroll
  for (int i = 0; i < CL; ++i) {
    re[i] = *(const float2*)(Bu + rbase + (size_t)i * DIMH + 2 * t);
    im[i] = *(const float2*)(Bu + rbase + (size_t)i * DIMH + PDIM + 2 * t);
  }
  const float2 l0 = lamb[2 * t];
  const float2 l1 = lamb[2 * t + 1];
  const size_t sb = ((size_t)bc * 2) * PDIM;
  const size_t obase = ((size_t)b * LSEQ + (size_t)c * CL) * 2048;
  {
    const float2 s0 = seed[sb + 2 * t];
    const float2 s1 = seed[sb + 2 * t + 1];
    float s0r = s0.x, s0i = s0.y, s1r = s1.x, s1i = s1.y;
#pragma unroll
    for (int i = 0; i < CL; ++i) {
      float nr = l0.x * s0r - l0.y * s0i + re[i].x;
      float ni = l0.x * s0i + l0.y * s0r + im[i].x;
      s0r = nr; s0i = ni;
      nr = l1.x * s1r - l1.y * s1i + re[i].y;
      ni = l1.x * s1i + l1.y * s1r + im[i].y;
      s1r = nr; s1i = ni;
      bf16x2 wr2 = { (bf16)s0r, (bf16)s1r };
      bf16x2 wi2 = { (bf16)s0i, (bf16)s1i };
      *(bf16x2*)(xs + obase + (size_t)i * 2048 + 2 * t) = wr2;
      *(bf16x2*)(xs + obase + (size_t)i * 2048 + PDIM + 2 * t) = wi2;
    }
  }
  {
    const float2 s0 = seed[sb + PDIM + 2 * t];
    const float2 s1 = seed[sb + PDIM + 2 * t + 1];
    float s0r = s0.x, s0i = s0.y, s1r = s1.x, s1i = s1.y;
#pragma unroll
    for (int i = CL - 1; i >= 0; --i) {
      float nr = l0.x * s0r - l0.y * s0i + re[i].x;
      float ni = l0.x * s0i + l0.y * s0r + im[i].x;
      s0r = nr; s0i = ni;
      nr = l1.x * s1r - l1.y * s1i + re[i].y;
      ni = l1.x * s1i + l1.y * s1r + im[i].y;
      s1r = nr; s1i = ni;
      bf16x2 wr2 = { (bf16)s0r, (bf16)s1r };
      bf16x2 wi2 = { (bf16)s0i, (bf16)s1i };
      *(bf16x2*)(xs + obase + (size_t)i * 2048 + 1024 + 2 * t) = wr2;
      *(bf16x2*)(xs + obase + (size_t)i * 2048 + 1536 + 2 * t) = wi2;
    }
  }
}

// ---------------------------------------------------------------- launch
extern "C" void kernel_launch(void* const* d_in, const int* in_sizes, int n_in,
                              void* d_out, int out_size, void* d_ws, size_t ws_size,
                              hipStream_t stream) {
  const float* x    = (const float*)d_in[0];
  const float* W_in = (const float*)d_in[1];
  const float* W_out= (const float*)d_in[2];
  const float* ln1w = (const float*)d_in[3];
  const float* ln1b = (const float*)d_in[4];
  const float* ln2w = (const float*)d_in[5];
  const float* ln2b = (const float*)d_in[6];
  const float* Lre  = (const float*)d_in[7];
  const float* Lim  = (const float*)d_in[8];
  const float* lstep= (const float*)d_in[9];
  const float* Bre  = (const float*)d_in[10];
  const float* Bim  = (const float*)d_in[11];
  const float* Cre  = (const float*)d_in[12];
  const float* Cim  = (const float*)d_in[13];
  const float* Dv   = (const float*)d_in[14];
  const float* ffe  = (const float*)d_in[15];
  const float* ffd  = (const float*)d_in[16];
  float* out = (float*)d_out;
  char* ws = (char*)d_ws;

  bf16* winb   = (bf16*)(ws);
  bf16* woutb  = (bf16*)(ws + (1u << 20));
  bf16* bcat   = (bf16*)(ws + (2u << 20));
  bf16* ccomb  = (bf16*)(ws + (4u << 20));
  bf16* ffeb   = (bf16*)(ws + (8u << 20));
  bf16* ffdb   = (bf16*)(ws + (12u << 20));
  float2* lamb = (float2*)(ws + (14u << 20));
  float2* coef = (float2*)(ws + (14u << 20) + 8192);
  bf16* E      = (bf16*)(ws + (16u << 20));        // 32MB bf16 slot
  float2* carry = (float2*)(ws + (16u << 20));     // overlaps E (lifetimes disjoint)
  float2* seed  = (float2*)(ws + (24u << 20));
  float* Abuf  = (float*)(ws + (48u << 20));       // 64MB
  float* Bbuf  = (float*)(ws + (112u << 20));      // 64MB
  float* Cbuf  = (float*)(ws + (176u << 20));      // 64MB: xs, later a_b|G
  bf16* xsb    = (bf16*)Cbuf;
  bf16* a_b    = (bf16*)Cbuf;                      // 32MB (after xs dead)
  bf16* G      = ((bf16*)Cbuf) + 16777216;         // 32MB

  // allow 128 KiB dynamic LDS for the GEMM instantiations
  static bool attr_done = false;
  if (!attr_done) {
    hipFuncSetAttribute((const void*)&k_gemm<0>, hipFuncAttributeMaxDynamicSharedMemorySize, 131072);
    hipFuncSetAttribute((const void*)&k_gemm<1>, hipFuncAttributeMaxDynamicSharedMemorySize, 131072);
    hipFuncSetAttribute((const void*)&k_gemm<2>, hipFuncAttributeMaxDynamicSharedMemorySize, 131072);
    hipFuncSetAttribute((const void*)&k_gemm<3>, hipFuncAttributeMaxDynamicSharedMemorySize, 131072);
    attr_done = true;
  }

  // prep
  k_prep<<<2, 256, 0, stream>>>(Lre, Lim, lstep, lamb, coef);
  k_f32_to_bf16<<<512, 256, 0, stream>>>(W_in, winb, 524288);
  k_f32_to_bf16<<<512, 256, 0, stream>>>(W_out, woutb, 524288);
  k_f32_to_bf16<<<2048, 256, 0, stream>>>(ffe, ffeb, 2097152);
  k_f32_to_bf16<<<1024, 256, 0, stream>>>(ffd, ffdb, 1048576);
  k_f32_to_bf16<<<8192, 256, 0, stream>>>(x, E, 8388608);  // x_b
  k_bcat<<<2048, 256, 0, stream>>>(Bre, Bim, coef, bcat);
  k_ccomb<<<8192, 256, 0, stream>>>(Cre, Cim, ccomb);

  // h = x @ W_in^T -> Abuf
  k_gemm<0><<<256, 512, 131072, stream>>>(E, winb, Abuf, nullptr, nullptr, nullptr, 512, 1024, 2);
  // fx = LN1(h) -> Bbuf(f32), E(bf16)
  k_ln<<<16384, 256, 0, stream>>>(Abuf, ln1w, ln1b, Bbuf, E);
  // Bu = fx @ Bcat^T -> Abuf
  k_gemm<0><<<256, 512, 131072, stream>>>(E, bcat, Abuf, nullptr, nullptr, nullptr, 1024, 1024, 2);
  // xs -> Cbuf (bf16) via 3-pass chunked scan
  k_scanA<<<4 * NC, 256, 0, stream>>>(Abuf, lamb, carry);
  k_scanB<<<4, 256, 0, stream>>>(carry, lamb, seed);
  k_scanC<<<4 * NC, 256, 0, stream>>>(Abuf, lamb, seed, xsb);
  // ys = xs @ Ccomb^T -> Abuf
  k_gemm<0><<<256, 512, 131072, stream>>>(xsb, ccomb, Abuf, nullptr, nullptr, nullptr, 2048, 1024, 2);
  // x2 = gelu(ys + D*fx) + fx; fx2 = LN2(x2) -> Bbuf (in place), E (bf16)
  k_ln2e<<<16384, 256, 0, stream>>>(Abuf, Bbuf, Dv, ln2w, ln2b, Bbuf, E);
  // a-half -> a_b (bf16)
  k_gemm<3><<<256, 512, 131072, stream>>>(E, ffeb, nullptr, a_b, nullptr, nullptr, 1024, 1024, 2);
  // g-half + fused geglu -> G (bf16)
  k_gemm<1><<<256, 512, 131072, stream>>>(E, ffeb + (size_t)1024 * 1024, nullptr, G, nullptr, a_b, 1024, 1024, 2);
  // ffo + residual -> E (bf16)
  k_gemm<2><<<256, 512, 131072, stream>>>(G, ffdb, nullptr, E, Bbuf, nullptr, 1024, 1024, 2);
  // out = x3 @ W_out^T
  k_gemm<0><<<128, 512, 131072, stream>>>(E, woutb, out, nullptr, nullptr, nullptr, 1024, 512, 1);
}

// Round 6
// 476.962 us; speedup vs baseline: 1.8930x; 1.0883x over previous
//
#include <hip/hip_runtime.h>
#include <cstdint>

typedef __bf16 bf16;
typedef __bf16 bf16x2 __attribute__((ext_vector_type(2)));
typedef __bf16 bf16x4 __attribute__((ext_vector_type(4)));
typedef __bf16 bf16x8 __attribute__((ext_vector_type(8)));
typedef float f32x4 __attribute__((ext_vector_type(4)));

#define MROWS 16384
#define DIMH 1024
#define PDIM 512
#define LSEQ 4096
#define CL 16
#define NC (LSEQ / CL)  // 256

typedef const __attribute__((address_space(1))) unsigned int* gas_t;
typedef __attribute__((address_space(3))) unsigned int* las_t;

__device__ __forceinline__ float gelu_f(float x) {
  return 0.5f * x * (1.0f + erff(x * 0.70710678118654752f));
}

// ---------------------------------------------------------------- small prep
__global__ void k_prep(const float* __restrict__ Lre, const float* __restrict__ Lim,
                       const float* __restrict__ lstep,
                       float2* __restrict__ lamb, float2* __restrict__ coef) {
  const int p = blockIdx.x * blockDim.x + threadIdx.x;
  if (p >= PDIM) return;
  const float lre = Lre[p], lim = Lim[p];
  const float st = expf(lstep[p]);
  const float er = expf(lre * st);
  const float lbr = er * cosf(lim * st);
  const float lbi = er * sinf(lim * st);
  lamb[p] = make_float2(lbr, lbi);
  const float ar = lbr - 1.0f, ai = lbi;
  const float d = lre * lre + lim * lim;
  coef[p] = make_float2((ar * lre + ai * lim) / d, (ai * lre - ar * lim) / d);
}

__global__ void k_f32_to_bf16(const float* __restrict__ in, bf16* __restrict__ outp, int n) {
  const int i = (blockIdx.x * 256 + threadIdx.x) * 4;
  if (i >= n) return;
  const float4 v = *(const float4*)(in + i);
  bf16x4 o = { (bf16)v.x, (bf16)v.y, (bf16)v.z, (bf16)v.w };
  *(bf16x4*)(outp + i) = o;
}

// bcat: rows 0..511 = Re(B_bar), rows 512..1023 = Im(B_bar)
__global__ void k_bcat(const float* __restrict__ Bre, const float* __restrict__ Bim,
                       const float2* __restrict__ coef, bf16* __restrict__ bcat) {
  const int idx = blockIdx.x * 256 + threadIdx.x;  // 512*1024
  const int p = idx >> 10;
  const float2 c = coef[p];
  const float br = Bre[idx], bi = Bim[idx];
  bcat[idx] = (bf16)(c.x * br - c.y * bi);
  bcat[idx + PDIM * DIMH] = (bf16)(c.x * bi + c.y * br);
}

// ccomb[n][k], k-layout [xsf_re | xsf_im | xsb_re | xsb_im]
__global__ void k_ccomb(const float* __restrict__ Cre, const float* __restrict__ Cim,
                        bf16* __restrict__ cc) {
  const int idx = blockIdx.x * 256 + threadIdx.x;  // 1024*2048
  const int n = idx >> 11, k = idx & 2047;
  float v;
  if (k < 512)       v =  2.0f * Cre[n * 1024 + k];
  else if (k < 1024) v = -2.0f * Cim[n * 1024 + (k - 512)];
  else if (k < 1536) v =  2.0f * Cre[n * 1024 + 512 + (k - 1024)];
  else               v = -2.0f * Cim[n * 1024 + 512 + (k - 1536)];
  cc[idx] = (bf16)v;
}

// ---------------------------------------------------------------- GEMM (256x256, 8-phase)
// C[M,N] = A[M,K] bf16 @ W[N,K]^T bf16.  8 waves (512 thr), BK=64 per K-tile,
// 2 K-tiles per iteration, counted vmcnt(4), raw barriers, LDS 128 KiB dynamic.
// LDS layout per operand: slot(2) x kkhalf(2) x [256 rows][32 cols] bf16,
// 16B-chunk XOR swizzle pc = lc ^ ((row>>1)&3).  B at byte offset 65536.
// EPI: 0 = f32 store; 1 = bf16(auxb * gelu(acc)); 2 = bf16(acc + auxb); 3 = bf16.

#define VMCNT4 asm volatile("s_waitcnt vmcnt(4)" ::: "memory")
#define VMCNT0 asm volatile("s_waitcnt vmcnt(0)" ::: "memory")
#define LGKM0  asm volatile("s_waitcnt lgkmcnt(0)" ::: "memory")
#define SCHED0 __builtin_amdgcn_sched_barrier(0)
#define BAR    __builtin_amdgcn_s_barrier()

#define PHASE(slot, kh, mh, LOADB, STAGE_STMT, WAIT_STMT)                      \
  {                                                                            \
    if (LOADB) ldB(slot, kh, bfr);                                             \
    ldA(slot, kh, mh, afr);                                                    \
    STAGE_STMT;                                                                \
    SCHED0;                                                                    \
    BAR;                                                                       \
    LGKM0;                                                                     \
    SCHED0;                                                                    \
    __builtin_amdgcn_s_setprio(1);                                             \
    _Pragma("unroll")                                                          \
    for (int m = 0; m < 4; ++m)                                                \
      _Pragma("unroll")                                                        \
      for (int n = 0; n < 4; ++n)                                              \
        acc[(mh) * 4 + m][n] = __builtin_amdgcn_mfma_f32_16x16x32_bf16(        \
            afr[m], bfr[n], acc[(mh) * 4 + m][n], 0, 0, 0);                    \
    __builtin_amdgcn_s_setprio(0);                                             \
    SCHED0;                                                                    \
    WAIT_STMT;                                                                 \
    BAR;                                                                       \
  }

template <int EPI>
__global__ __launch_bounds__(512, 2) void k_gemm(const bf16* __restrict__ A,
                                                 const bf16* __restrict__ W,
                                                 float* __restrict__ Cf,
                                                 bf16* __restrict__ Cb,
                                                 const bf16* __restrict__ auxb,
                                                 int K, int N, int nbnl) {
  extern __shared__ char lds[];  // 131072 bytes
  const int q = (int)gridDim.x >> 3;
  const int s = ((int)blockIdx.x & 7) * q + ((int)blockIdx.x >> 3);
  const int bm = s >> nbnl;
  const int bn = s & ((1 << nbnl) - 1);
  const int tid = threadIdx.x;
  const int lane = tid & 63;
  const int wave = tid >> 6;
  const int wr = wave >> 2;  // 0..1
  const int wc = wave & 3;   // 0..3

  const size_t arow0 = (size_t)bm * 256;
  const size_t wrow0 = (size_t)bn * 256;
  const int srow = tid >> 2;                         // 0..127 per issue
  const int schunk = (tid & 3) ^ ((tid >> 3) & 3);   // inverse-swizzled src chunk
  const int wbase = wave << 10;                      // wave-uniform LDS sub-base

  f32x4 acc[8][4];
#pragma unroll
  for (int i = 0; i < 8; ++i)
#pragma unroll
    for (int j = 0; j < 4; ++j) acc[i][j] = (f32x4){0.f, 0.f, 0.f, 0.f};

  // stage one (slot, kkhalf) group: A(2 issues) + B(2 issues) = 4 loads/wave
  auto stage = [&](int slot, int kh, int kt) {
    const int kcol = kt * 64 + kh * 32 + schunk * 8;
    {
      char* base = lds + slot * 32768 + kh * 16384;
      __builtin_amdgcn_global_load_lds(
          (gas_t)(A + (arow0 + srow) * (size_t)K + kcol), (las_t)(base + wbase), 16, 0, 0);
      __builtin_amdgcn_global_load_lds(
          (gas_t)(A + (arow0 + 128 + srow) * (size_t)K + kcol), (las_t)(base + 8192 + wbase), 16, 0, 0);
    }
    {
      char* base = lds + 65536 + slot * 32768 + kh * 16384;
      __builtin_amdgcn_global_load_lds(
          (gas_t)(W + (wrow0 + srow) * (size_t)K + kcol), (las_t)(base + wbase), 16, 0, 0);
      __builtin_amdgcn_global_load_lds(
          (gas_t)(W + (wrow0 + 128 + srow) * (size_t)K + kcol), (las_t)(base + 8192 + wbase), 16, 0, 0);
    }
  };

  auto ldA = [&](int slot, int kh, int mh, bf16x8* af) {
#pragma unroll
    for (int m = 0; m < 4; ++m) {
      const int row = wr * 128 + mh * 64 + m * 16 + (lane & 15);
      const int pc = (lane >> 4) ^ ((row >> 1) & 3);
      af[m] = *(const bf16x8*)(lds + slot * 32768 + kh * 16384 + row * 64 + pc * 16);
    }
  };
  auto ldB = [&](int slot, int kh, bf16x8* bf) {
#pragma unroll
    for (int n = 0; n < 4; ++n) {
      const int row = wc * 64 + n * 16 + (lane & 15);
      const int pc = (lane >> 4) ^ ((row >> 1) & 3);
      bf[n] = *(const bf16x8*)(lds + 65536 + slot * 32768 + kh * 16384 + row * 64 + pc * 16);
    }
  };

  bf16x8 afr[4], bfr[4];

  // prologue: slot0 fully (kt0), slot1.kh0 (kt1); complete slot0, leave rest in flight
  stage(0, 0, 0);
  stage(0, 1, 0);
  stage(1, 0, 1);
  VMCNT4;
  BAR;

  const int NT = K >> 7;  // K/128 iterations, 2 K-tiles each
  for (int t = 0; t < NT; ++t) {
    const int nl = (t + 1 < NT);
    PHASE(0, 0, 0, 1, stage(1, 1, 2 * t + 1), (void)0);
    PHASE(0, 0, 1, 0, (void)0, (void)0);
    PHASE(0, 1, 0, 1, if (nl) stage(0, 0, 2 * t + 2), (void)0);
    if (nl) { PHASE(0, 1, 1, 0, (void)0, VMCNT4); }
    else    { PHASE(0, 1, 1, 0, (void)0, VMCNT0); }
    PHASE(1, 0, 0, 1, if (nl) stage(0, 1, 2 * t + 2), (void)0);
    PHASE(1, 0, 1, 0, (void)0, (void)0);
    PHASE(1, 1, 0, 1, if (nl) stage(1, 0, 2 * t + 3), (void)0);
    if (nl) { PHASE(1, 1, 1, 0, (void)0, VMCNT4); }
    else    { PHASE(1, 1, 1, 0, (void)0, (void)0); }
  }

  // epilogue: C-quadrant write.  col = lane&15, row = (lane>>4)*4 + r
  const int n0 = (int)wrow0 + wc * 64 + (lane & 15);
  const size_t m0 = arow0 + wr * 128 + ((lane >> 4) << 2);
#pragma unroll
  for (int mi = 0; mi < 8; ++mi)
#pragma unroll
    for (int n = 0; n < 4; ++n) {
      const size_t mb = m0 + mi * 16;
      const int nn = n0 + n * 16;
#pragma unroll
      for (int r = 0; r < 4; ++r) {
        const size_t idx = (mb + r) * (size_t)N + nn;
        const float v = acc[mi][n][r];
        if constexpr (EPI == 0) {
          Cf[idx] = v;
        } else if constexpr (EPI == 1) {
          Cb[idx] = (bf16)((float)auxb[idx] * gelu_f(v));
        } else if constexpr (EPI == 2) {
          Cb[idx] = (bf16)(v + (float)auxb[idx]);
        } else {
          Cb[idx] = (bf16)v;
        }
      }
    }
}

// ---------------------------------------------------------------- LayerNorm (bf16 in/out)
__global__ __launch_bounds__(256) void k_ln(const bf16* __restrict__ X,
                                            const float* __restrict__ w,
                                            const float* __restrict__ bb,
                                            bf16* __restrict__ Yb) {
  const int m = blockIdx.x;
  const int tid = threadIdx.x;
  const bf16x4 v4 = *(const bf16x4*)(X + (size_t)m * DIMH + tid * 4);
  const float v0 = (float)v4[0], v1 = (float)v4[1], v2 = (float)v4[2], v3 = (float)v4[3];
  float s = v0 + v1 + v2 + v3;
  float s2 = v0 * v0 + v1 * v1 + v2 * v2 + v3 * v3;
#pragma unroll
  for (int off = 32; off > 0; off >>= 1) { s += __shfl_down(s, off); s2 += __shfl_down(s2, off); }
  __shared__ float rs[4], rq[4];
  if ((tid & 63) == 0) { rs[tid >> 6] = s; rq[tid >> 6] = s2; }
  __syncthreads();
  s = rs[0] + rs[1] + rs[2] + rs[3];
  s2 = rq[0] + rq[1] + rq[2] + rq[3];
  const float mu = s * (1.0f / DIMH);
  const float inv = rsqrtf(s2 * (1.0f / DIMH) - mu * mu + 1e-5f);
  const float4 wv = ((const float4*)w)[tid];
  const float4 bv = ((const float4*)bb)[tid];
  bf16x4 ob = { (bf16)((v0 - mu) * inv * wv.x + bv.x), (bf16)((v1 - mu) * inv * wv.y + bv.y),
                (bf16)((v2 - mu) * inv * wv.z + bv.z), (bf16)((v3 - mu) * inv * wv.w + bv.w) };
  *(bf16x4*)(Yb + (size_t)m * DIMH + tid * 4) = ob;
}

// fused: t = gelu(ys + D*fx) + fx ; LN(t) -> fx2, written in-place into FXE
__global__ __launch_bounds__(256) void k_ln2e(const bf16* __restrict__ YS,
                                              bf16* FXE,
                                              const float* __restrict__ Dv,
                                              const float* __restrict__ w,
                                              const float* __restrict__ bb) {
  const int m = blockIdx.x;
  const int tid = threadIdx.x;
  const bf16x4 ys4 = *(const bf16x4*)(YS + (size_t)m * DIMH + tid * 4);
  const bf16x4 fx4 = *(const bf16x4*)(FXE + (size_t)m * DIMH + tid * 4);
  const float4 dv = ((const float4*)Dv)[tid];
  const float f0 = (float)fx4[0], f1 = (float)fx4[1], f2 = (float)fx4[2], f3 = (float)fx4[3];
  const float t0 = gelu_f((float)ys4[0] + dv.x * f0) + f0;
  const float t1 = gelu_f((float)ys4[1] + dv.y * f1) + f1;
  const float t2 = gelu_f((float)ys4[2] + dv.z * f2) + f2;
  const float t3 = gelu_f((float)ys4[3] + dv.w * f3) + f3;
  float s = t0 + t1 + t2 + t3;
  float s2 = t0 * t0 + t1 * t1 + t2 * t2 + t3 * t3;
#pragma unroll
  for (int off = 32; off > 0; off >>= 1) { s += __shfl_down(s, off); s2 += __shfl_down(s2, off); }
  __shared__ float rs[4], rq[4];
  if ((tid & 63) == 0) { rs[tid >> 6] = s; rq[tid >> 6] = s2; }
  __syncthreads();
  s = rs[0] + rs[1] + rs[2] + rs[3];
  s2 = rq[0] + rq[1] + rq[2] + rq[3];
  const float mu = s * (1.0f / DIMH);
  const float inv = rsqrtf(s2 * (1.0f / DIMH) - mu * mu + 1e-5f);
  const float4 wv = ((const float4*)w)[tid];
  const float4 bv = ((const float4*)bb)[tid];
  bf16x4 ob = { (bf16)((t0 - mu) * inv * wv.x + bv.x), (bf16)((t1 - mu) * inv * wv.y + bv.y),
                (bf16)((t2 - mu) * inv * wv.z + bv.z), (bf16)((t3 - mu) * inv * wv.w + bv.w) };
  *(bf16x4*)(FXE + (size_t)m * DIMH + tid * 4) = ob;
}

// ---------------------------------------------------------------- scan (3-pass, bf16 Bu)
__global__ __launch_bounds__(256) void k_scanA(const bf16* __restrict__ Bu,
                                               const float2* __restrict__ lamb,
                                               float2* __restrict__ carry) {
  const int bc = blockIdx.x;
  const int b = bc >> 8, c = bc & (NC - 1);
  const int t = threadIdx.x;
  const size_t rbase = ((size_t)b * LSEQ + (size_t)c * CL) * DIMH;
  float2 re[CL], im[CL];
#pragma unroll
  for (int i = 0; i < CL; ++i) {
    const bf16x2 r2 = *(const bf16x2*)(Bu + rbase + (size_t)i * DIMH + 2 * t);
    const bf16x2 i2 = *(const bf16x2*)(Bu + rbase + (size_t)i * DIMH + PDIM + 2 * t);
    re[i] = make_float2((float)r2[0], (float)r2[1]);
    im[i] = make_float2((float)i2[0], (float)i2[1]);
  }
  const float2 l0 = lamb[2 * t];
  const float2 l1 = lamb[2 * t + 1];
  const size_t cb = ((size_t)bc * 2) * PDIM;
  {
    float s0r = 0.f, s0i = 0.f, s1r = 0.f, s1i = 0.f;
#pragma unroll
    for (int i = 0; i < CL; ++i) {
      float nr = l0.x * s0r - l0.y * s0i + re[i].x;
      float ni = l0.x * s0i + l0.y * s0r + im[i].x;
      s0r = nr; s0i = ni;
      nr = l1.x * s1r - l1.y * s1i + re[i].y;
      ni = l1.x * s1i + l1.y * s1r + im[i].y;
      s1r = nr; s1i = ni;
    }
    carry[cb + 2 * t]     = make_float2(s0r, s0i);
    carry[cb + 2 * t + 1] = make_float2(s1r, s1i);
  }
  {
    float s0r = 0.f, s0i = 0.f, s1r = 0.f, s1i = 0.f;
#pragma unroll
    for (int i = CL - 1; i >= 0; --i) {
      float nr = l0.x * s0r - l0.y * s0i + re[i].x;
      float ni = l0.x * s0i + l0.y * s0r + im[i].x;
      s0r = nr; s0i = ni;
      nr = l1.x * s1r - l1.y * s1i + re[i].y;
      ni = l1.x * s1i + l1.y * s1r + im[i].y;
      s1r = nr; s1i = ni;
    }
    carry[cb + PDIM + 2 * t]     = make_float2(s0r, s0i);
    carry[cb + PDIM + 2 * t + 1] = make_float2(s1r, s1i);
  }
}

__global__ __launch_bounds__(256) void k_scanB(const float2* __restrict__ carry,
                                               const float2* __restrict__ lamb,
                                               float2* __restrict__ seed) {
  const int b = blockIdx.x;  // 4 blocks
  const int t = threadIdx.x;
  const float2 l0 = lamb[2 * t], l1 = lamb[2 * t + 1];
  float L0r = l0.x, L0i = l0.y, L1r = l1.x, L1i = l1.y;
#pragma unroll
  for (int q = 0; q < 4; ++q) {
    float tr = L0r * L0r - L0i * L0i; L0i = 2.f * L0r * L0i; L0r = tr;
    tr = L1r * L1r - L1i * L1i; L1i = 2.f * L1r * L1i; L1r = tr;
  }
  float S0r = 0.f, S0i = 0.f, S1r = 0.f, S1i = 0.f;
  for (int c = 0; c < NC; ++c) {
    const size_t base = (((size_t)b * NC + c) * 2) * PDIM;
    const float2 c0 = carry[base + 2 * t];
    const float2 c1 = carry[base + 2 * t + 1];
    seed[base + 2 * t]     = make_float2(S0r, S0i);
    seed[base + 2 * t + 1] = make_float2(S1r, S1i);
    float nr = L0r * S0r - L0i * S0i + c0.x;
    float ni = L0r * S0i + L0i * S0r + c0.y;
    S0r = nr; S0i = ni;
    nr = L1r * S1r - L1i * S1i + c1.x;
    ni = L1r * S1i + L1i * S1r + c1.y;
    S1r = nr; S1i = ni;
  }
  S0r = 0.f; S0i = 0.f; S1r = 0.f; S1i = 0.f;
  for (int c = NC - 1; c >= 0; --c) {
    const size_t base = (((size_t)b * NC + c) * 2) * PDIM + PDIM;
    const float2 c0 = carry[base + 2 * t];
    const float2 c1 = carry[base + 2 * t + 1];
    seed[base + 2 * t]     = make_float2(S0r, S0i);
    seed[base + 2 * t + 1] = make_float2(S1r, S1i);
    float nr = L0r * S0r - L0i * S0i + c0.x;
    float ni = L0r * S0i + L0i * S0r + c0.y;
    S0r = nr; S0i = ni;
    nr = L1r * S1r - L1i * S1i + c1.x;
    ni = L1r * S1i + L1i * S1r + c1.y;
    S1r = nr; S1i = ni;
  }
}

__global__ __launch_bounds__(256) void k_scanC(const bf16* __restrict__ Bu,
                                               const float2* __restrict__ lamb,
                                               const float2* __restrict__ seed,
                                               bf16* __restrict__ xs) {
  const int bc = blockIdx.x;
  const int b = bc >> 8, c = bc & (NC - 1);
  const int t = threadIdx.x;
  const size_t rbase = ((size_t)b * LSEQ + (size_t)c * CL) * DIMH;
  float2 re[CL], im[CL];
#pragma unroll
  for (int i = 0; i < CL; ++i) {
    const bf16x2 r2 = *(const bf16x2*)(Bu + rbase + (size_t)i * DIMH + 2 * t);
    const bf16x2 i2 = *(const bf16x2*)(Bu + rbase + (size_t)i * DIMH + PDIM + 2 * t);
    re[i] = make_float2((float)r2[0], (float)r2[1]);
    im[i] = make_float2((float)i2[0], (float)i2[1]);
  }
  const float2 l0 = lamb[2 * t];
  const float2 l1 = lamb[2 * t + 1];
  const size_t sb = ((size_t)bc * 2) * PDIM;
  const size_t obase = ((size_t)b * LSEQ + (size_t)c * CL) * 2048;
  {
    const float2 s0 = seed[sb + 2 * t];
    const float2 s1 = seed[sb + 2 * t + 1];
    float s0r = s0.x, s0i = s0.y, s1r = s1.x, s1i = s1.y;
#pragma unroll
    for (int i = 0; i < CL; ++i) {
      float nr = l0.x * s0r - l0.y * s0i + re[i].x;
      float ni = l0.x * s0i + l0.y * s0r + im[i].x;
      s0r = nr; s0i = ni;
      nr = l1.x * s1r - l1.y * s1i + re[i].y;
      ni = l1.x * s1i + l1.y * s1r + im[i].y;
      s1r = nr; s1i = ni;
      bf16x2 wr2 = { (bf16)s0r, (bf16)s1r };
      bf16x2 wi2 = { (bf16)s0i, (bf16)s1i };
      *(bf16x2*)(xs + obase + (size_t)i * 2048 + 2 * t) = wr2;
      *(bf16x2*)(xs + obase + (size_t)i * 2048 + PDIM + 2 * t) = wi2;
    }
  }
  {
    const float2 s0 = seed[sb + PDIM + 2 * t];
    const float2 s1 = seed[sb + PDIM + 2 * t + 1];
    float s0r = s0.x, s0i = s0.y, s1r = s1.x, s1i = s1.y;
#pragma unroll
    for (int i = CL - 1; i >= 0; --i) {
      float nr = l0.x * s0r - l0.y * s0i + re[i].x;
      float ni = l0.x * s0i + l0.y * s0r + im[i].x;
      s0r = nr; s0i = ni;
      nr = l1.x * s1r - l1.y * s1i + re[i].y;
      ni = l1.x * s1i + l1.y * s1r + im[i].y;
      s1r = nr; s1i = ni;
      bf16x2 wr2 = { (bf16)s0r, (bf16)s1r };
      bf16x2 wi2 = { (bf16)s0i, (bf16)s1i };
      *(bf16x2*)(xs + obase + (size_t)i * 2048 + 1024 + 2 * t) = wr2;
      *(bf16x2*)(xs + obase + (size_t)i * 2048 + 1536 + 2 * t) = wi2;
    }
  }
}

// ---------------------------------------------------------------- launch
extern "C" void kernel_launch(void* const* d_in, const int* in_sizes, int n_in,
                              void* d_out, int out_size, void* d_ws, size_t ws_size,
                              hipStream_t stream) {
  const float* x    = (const float*)d_in[0];
  const float* W_in = (const float*)d_in[1];
  const float* W_out= (const float*)d_in[2];
  const float* ln1w = (const float*)d_in[3];
  const float* ln1b = (const float*)d_in[4];
  const float* ln2w = (const float*)d_in[5];
  const float* ln2b = (const float*)d_in[6];
  const float* Lre  = (const float*)d_in[7];
  const float* Lim  = (const float*)d_in[8];
  const float* lstep= (const float*)d_in[9];
  const float* Bre  = (const float*)d_in[10];
  const float* Bim  = (const float*)d_in[11];
  const float* Cre  = (const float*)d_in[12];
  const float* Cim  = (const float*)d_in[13];
  const float* Dv   = (const float*)d_in[14];
  const float* ffe  = (const float*)d_in[15];
  const float* ffd  = (const float*)d_in[16];
  float* out = (float*)d_out;
  char* ws = (char*)d_ws;

  bf16* winb   = (bf16*)(ws);
  bf16* woutb  = (bf16*)(ws + (1u << 20));
  bf16* bcat   = (bf16*)(ws + (2u << 20));
  bf16* ccomb  = (bf16*)(ws + (4u << 20));
  bf16* ffeb   = (bf16*)(ws + (8u << 20));
  bf16* ffdb   = (bf16*)(ws + (12u << 20));
  float2* lamb = (float2*)(ws + (14u << 20));
  float2* coef = (float2*)(ws + (14u << 20) + 8192);
  bf16* E      = (bf16*)(ws + (16u << 20));        // 32MB: x_b -> fx -> fx2
  bf16* hb     = (bf16*)(ws + (48u << 20));        // 32MB: h
  bf16* Bub    = (bf16*)(ws + (48u << 20));        // reuse (h dead after k_ln)
  bf16* ysb    = (bf16*)(ws + (48u << 20));        // reuse (Bu dead after scanC)
  bf16* x3b    = (bf16*)(ws + (48u << 20));        // reuse (ys dead after ln2e)
  bf16* xsb    = (bf16*)(ws + (80u << 20));        // 64MB: xs
  bf16* a_b    = (bf16*)(ws + (80u << 20));        // reuse (xs dead after C-proj)
  bf16* G      = (bf16*)(ws + (112u << 20));       // 32MB
  float2* carry = (float2*)(ws + (144u << 20));    // 8MB
  float2* seed  = (float2*)(ws + (152u << 20));    // 8MB

  // allow 128 KiB dynamic LDS for the GEMM instantiations
  static bool attr_done = false;
  if (!attr_done) {
    hipFuncSetAttribute((const void*)&k_gemm<0>, hipFuncAttributeMaxDynamicSharedMemorySize, 131072);
    hipFuncSetAttribute((const void*)&k_gemm<1>, hipFuncAttributeMaxDynamicSharedMemorySize, 131072);
    hipFuncSetAttribute((const void*)&k_gemm<2>, hipFuncAttributeMaxDynamicSharedMemorySize, 131072);
    hipFuncSetAttribute((const void*)&k_gemm<3>, hipFuncAttributeMaxDynamicSharedMemorySize, 131072);
    attr_done = true;
  }

  // prep
  k_prep<<<2, 256, 0, stream>>>(Lre, Lim, lstep, lamb, coef);
  k_f32_to_bf16<<<512, 256, 0, stream>>>(W_in, winb, 524288);
  k_f32_to_bf16<<<512, 256, 0, stream>>>(W_out, woutb, 524288);
  k_f32_to_bf16<<<2048, 256, 0, stream>>>(ffe, ffeb, 2097152);
  k_f32_to_bf16<<<1024, 256, 0, stream>>>(ffd, ffdb, 1048576);
  k_f32_to_bf16<<<8192, 256, 0, stream>>>(x, E, 8388608);  // x_b
  k_bcat<<<2048, 256, 0, stream>>>(Bre, Bim, coef, bcat);
  k_ccomb<<<8192, 256, 0, stream>>>(Cre, Cim, ccomb);

  // h = x @ W_in^T -> hb (bf16)
  k_gemm<3><<<256, 512, 131072, stream>>>(E, winb, nullptr, hb, nullptr, 512, 1024, 2);
  // fx = LN1(h) -> E (bf16)
  k_ln<<<16384, 256, 0, stream>>>(hb, ln1w, ln1b, E);
  // Bu = fx @ Bcat^T -> Bub (bf16)
  k_gemm<3><<<256, 512, 131072, stream>>>(E, bcat, nullptr, Bub, nullptr, 1024, 1024, 2);
  // xs -> xsb (bf16) via 3-pass chunked scan
  k_scanA<<<4 * NC, 256, 0, stream>>>(Bub, lamb, carry);
  k_scanB<<<4, 256, 0, stream>>>(carry, lamb, seed);
  k_scanC<<<4 * NC, 256, 0, stream>>>(Bub, lamb, seed, xsb);
  // ys = xs @ Ccomb^T -> ysb (bf16)
  k_gemm<3><<<256, 512, 131072, stream>>>(xsb, ccomb, nullptr, ysb, nullptr, 2048, 1024, 2);
  // x2 = gelu(ys + D*fx) + fx; fx2 = LN2(x2) -> E in place (bf16)
  k_ln2e<<<16384, 256, 0, stream>>>(ysb, E, Dv, ln2w, ln2b);
  // a-half -> a_b (bf16)
  k_gemm<3><<<256, 512, 131072, stream>>>(E, ffeb, nullptr, a_b, nullptr, 1024, 1024, 2);
  // g-half + fused geglu -> G (bf16)
  k_gemm<1><<<256, 512, 131072, stream>>>(E, ffeb + (size_t)1024 * 1024, nullptr, G, a_b, 1024, 1024, 2);
  // ffo + residual(fx2) -> x3b (bf16)
  k_gemm<2><<<256, 512, 131072, stream>>>(G, ffdb, nullptr, x3b, E, 1024, 1024, 2);
  // out = x3 @ W_out^T (f32)
  k_gemm<0><<<128, 512, 131072, stream>>>(x3b, woutb, out, nullptr, nullptr, 1024, 512, 1);
}